// Round 6
// baseline (894.223 us; speedup 1.0000x reference)
//
#include <hip/hip_runtime.h>
#include <hip/hip_bf16.h>
#include <math.h>

// N=200000 nodes, U=100000 users, D=64, L=3, E=3,000,000 per edge list, NLINK=100000.
// ws: 3 bf16 node bufs (76.8MB) + 2 bin/col (24MB, sorted in place) + aux ~= 104MB.

typedef unsigned short u16;
typedef unsigned int   u32;
typedef __attribute__((ext_vector_type(8))) short bf16x8;
typedef __attribute__((ext_vector_type(4))) float f32x4;

#define BSHIFT 9                 // 512 nodes per coarse bucket
#define BWIDTH 512
#define BCAP   8192              // LDS staging per sort bucket
#define OVF    8                 // +2048 entries of per-thread register headroom
#define HCHUNK 8192              // edges per hist block
#define BCHUNK 16384             // edges per bin block

__device__ __forceinline__ float bf2f(u16 v) {
    u32 x = ((u32)v) << 16;
    return __builtin_bit_cast(float, x);
}
__device__ __forceinline__ u16 f2bf(float f) {
    u32 x = __builtin_bit_cast(u32, f);
    u32 r = x + 0x7fffu + ((x >> 16) & 1u);   // round-to-nearest-even
    return (u16)(r >> 16);
}
__device__ __forceinline__ u32 pack2(float a, float b) {
    return (u32)f2bf(a) | ((u32)f2bf(b) << 16);
}
__device__ __forceinline__ float flo(u32 p) { return __builtin_bit_cast(float, p << 16); }
__device__ __forceinline__ float fhi(u32 p) { return __builtin_bit_cast(float, p & 0xffff0000u); }
__device__ __forceinline__ int imin(int a, int b) { return a < b ? a : b; }

// ---- D1: fused hist(s) + hist(t) + W->bf16 prep + emb->bf16 staging ----
__global__ __launch_bounds__(256) void prep_hist(const int* __restrict__ sdst,
        const int* __restrict__ tdst, int e, int* __restrict__ gcnt2,
        const float* __restrict__ mw, u16* __restrict__ mwb,
        const float* __restrict__ emb, u32* __restrict__ embb, int nelem,
        int nhist, int nwprep) {
    __shared__ int lcnt[BWIDTH];
    int bid = blockIdx.x, tid = threadIdx.x;
    if (bid < 2 * nhist) {
        const int* dst = (bid < nhist) ? sdst : tdst;
        int* gcnt = gcnt2 + ((bid < nhist) ? 0 : BWIDTH);
        int cb = (bid < nhist) ? bid : bid - nhist;
        for (int i = tid; i < BWIDTH; i += 256) lcnt[i] = 0;
        __syncthreads();
        int base = cb * HCHUNK, end = imin(base + HCHUNK, e);
        for (int i = base + tid; i < end; i += 256)
            atomicAdd(&lcnt[(u32)dst[i] >> BSHIFT], 1);
        __syncthreads();
        for (int i = tid; i < BWIDTH; i += 256)
            if (lcnt[i]) atomicAdd(&gcnt[i], lcnt[i]);
    } else if (bid < 2 * nhist + nwprep) {
        int idx = (bid - 2 * nhist) * 256 + tid;
        if (idx < 3 * 64 * 128) mwb[idx] = f2bf(mw[idx]);
    } else {
        int idx = (bid - 2 * nhist - nwprep) * 1024 + tid * 4;   // 4 floats / thread
        if (idx < nelem) {
            float4 v = *(const float4*)(emb + idx);
            uint2 r;
            r.x = pack2(v.x, v.y);
            r.y = pack2(v.z, v.w);
            *(uint2*)(embb + (idx >> 1)) = r;
        }
    }
}

// ---- D2: parallel bucket scans (2 blocks) + pred0 (layer-0 term, fp32 emb) ----
__global__ __launch_bounds__(256) void scan_pred0(const int* __restrict__ gcnt2, int nb,
        int* __restrict__ bbase_s, int* __restrict__ bbase_t, int* __restrict__ cur2,
        int* __restrict__ rs_s, int* __restrict__ rs_t, int n,
        const float* __restrict__ emb, const int* __restrict__ l0, const int* __restrict__ l1,
        const float* __restrict__ pw, float* __restrict__ acc, int nl) {
    int bid = blockIdx.x;
    int tid = threadIdx.x;
    if (bid < 2) {
        __shared__ int part[256];
        const int* g = gcnt2 + bid * BWIDTH;
        int* bb = bid ? bbase_t : bbase_s;
        int* cu = cur2 + bid * BWIDTH;
        int* rs = bid ? rs_t : rs_s;
        int i0 = tid * 2;
        int c0 = g[i0], c1 = g[i0 + 1];
        int s = c0 + c1;
        part[tid] = s;
        __syncthreads();
        for (int off = 1; off < 256; off <<= 1) {
            int t = (tid >= off) ? part[tid - off] : 0;
            __syncthreads();
            part[tid] += t;
            __syncthreads();
        }
        int excl = part[tid] - s;
        if (i0 <= nb)     { bb[i0] = excl; }
        if (i0 + 1 <= nb) { bb[i0 + 1] = excl + c0; }
        if (i0 < nb)      cu[i0] = excl;
        if (i0 + 1 < nb)  cu[i0 + 1] = excl + c0;
        if (tid == 255)   rs[n] = part[255];
        return;
    }
    int li = (bid - 2) * 4 + (tid >> 6);
    if (li >= nl) return;
    li = __builtin_amdgcn_readfirstlane(li);
    int lane = tid & 63;
    int u = l0[li], v = l1[li];
    float s = pw[lane] * emb[(size_t)u * 64 + lane] + pw[256 + lane] * emb[(size_t)v * 64 + lane];
#pragma unroll
    for (int off = 32; off > 0; off >>= 1) s += __shfl_xor(s, off, 64);
    if (lane == 0) acc[li] = s;
}

// ---- D3: fused binning (both lists) ----
__global__ __launch_bounds__(256) void bin2_kernel(const int* __restrict__ ssrc,
        const int* __restrict__ sdst, const int* __restrict__ tsrc, const int* __restrict__ tdst,
        int e, int* __restrict__ cur2, u32* __restrict__ bin_s, u32* __restrict__ bin_t,
        int nbin) {
    __shared__ int lcnt[BWIDTH];
    __shared__ int lbase[BWIDTH];
    int bid = blockIdx.x, tid = threadIdx.x;
    const int* src; const int* dst; int* cursor; u32* bin; int cb;
    if (bid < nbin) { src = ssrc; dst = sdst; cursor = cur2; bin = bin_s; cb = bid; }
    else { src = tsrc; dst = tdst; cursor = cur2 + BWIDTH; bin = bin_t; cb = bid - nbin; }
    for (int i = tid; i < BWIDTH; i += 256) lcnt[i] = 0;
    __syncthreads();
    int base = cb * BCHUNK, end = imin(base + BCHUNK, e);
    for (int i = base + tid; i < end; i += 256)
        atomicAdd(&lcnt[(u32)dst[i] >> BSHIFT], 1);
    __syncthreads();
    for (int i = tid; i < BWIDTH; i += 256) {
        int c = lcnt[i];
        lbase[i] = c ? atomicAdd(&cursor[i], c) : 0;
        lcnt[i] = 0;
    }
    __syncthreads();
    for (int i = base + tid; i < end; i += 256) {
        int d = dst[i];
        int b = (u32)d >> BSHIFT;
        int pos = lbase[b] + atomicAdd(&lcnt[b], 1);
        bin[pos] = (u32)src[i] | ((u32)(d & (BWIDTH - 1)) << 18);   // src < 2^18
    }
}

// ---- D4: fused per-bucket counting sort (both lists), in place ----
__global__ __launch_bounds__(256) void sort2_kernel(u32* __restrict__ bin_s, u32* __restrict__ bin_t,
        const int* __restrict__ bbase_s, const int* __restrict__ bbase_t,
        int* __restrict__ rs_s, int* __restrict__ rs_t, int n, int nb) {
    __shared__ u32 ent[BCAP];
    __shared__ int cnt[BWIDTH];
    __shared__ int part[256];
    int bid = blockIdx.x, tid = threadIdx.x;
    u32* bin; const int* bbase; int* rowstart; int b;
    if (bid < nb) { bin = bin_s; bbase = bbase_s; rowstart = rs_s; b = bid; }
    else { bin = bin_t; bbase = bbase_t; rowstart = rs_t; b = bid - nb; }
    int beg = bbase[b], end = bbase[b + 1];
    int sz = end - beg;
    for (int i = tid; i < BWIDTH; i += 256) cnt[i] = 0;
    __syncthreads();
    u32 ovf[OVF];
    for (int i = tid; i < sz; i += 256) {
        u32 v = bin[beg + i];
        if (i < BCAP) ent[i] = v;
        else { int k = (i - BCAP) >> 8; if (k < OVF) ovf[k] = v; }
        atomicAdd(&cnt[v >> 18], 1);
    }
    __syncthreads();
    int l0 = tid * 2;
    int c0 = cnt[l0], c1 = cnt[l0 + 1];
    int s = c0 + c1;
    part[tid] = s;
    __syncthreads();
    for (int off = 1; off < 256; off <<= 1) {
        int t = (tid >= off) ? part[tid - off] : 0;
        __syncthreads();
        part[tid] += t;
        __syncthreads();
    }
    int excl = part[tid] - s;
    int node = (b << BSHIFT) + l0;
    if (node < n)     rowstart[node]     = beg + excl;
    if (node + 1 < n) rowstart[node + 1] = beg + excl + c0;
    cnt[l0]     = excl;
    cnt[l0 + 1] = excl + c0;
    __syncthreads();
    for (int i = tid; i < sz; i += 256) {
        u32 v;
        if (i < BCAP) v = ent[i];
        else { int k = (i - BCAP) >> 8; v = (k < OVF) ? ovf[k] : bin[beg + i]; }
        int pos = atomicAdd(&cnt[v >> 18], 1);
        bin[beg + pos] = v & 0x3FFFFu;
    }
}

// ---- mean aggregation (bf16 in/out) + optional fused predictor blocks ----
// One wave per dst node; 8 lanes/edge (uint4 = 16B), 8 edge groups, 8-edge blocks.
// No per-iteration masks: clamped slots overcount row[col[deg-1]], subtracted once
// after the loop. Col load for the next block is software-pipelined.
__global__ __launch_bounds__(256) void aggp_kernel(
        const u32* __restrict__ x0, const int* __restrict__ rsA, const u32* __restrict__ colA,
        u32* __restrict__ outA, int nblkA,
        const u32* __restrict__ x1, const int* __restrict__ rsB, const u32* __restrict__ colB,
        u32* __restrict__ outB, int nblkB, int n,
        const u16* __restrict__ px, const int* __restrict__ l0, const int* __restrict__ l1,
        const float* __restrict__ pw, int ofA, int ofB, float* __restrict__ acc, int nl,
        int npred) {
    int bid = blockIdx.x;
    int lane = threadIdx.x & 63;
    if (bid < npred) {
        int li = bid * 4 + (threadIdx.x >> 6);
        if (li >= nl) return;
        li = __builtin_amdgcn_readfirstlane(li);
        int u = l0[li], v = l1[li];
        float s = pw[ofA + lane] * bf2f(px[(size_t)u * 64 + lane])
                + pw[ofB + lane] * bf2f(px[(size_t)v * 64 + lane]);
#pragma unroll
        for (int off = 32; off > 0; off >>= 1) s += __shfl_xor(s, off, 64);
        if (lane == 0) acc[li] += s;
        return;
    }
    bid -= npred;
    const u32* xin; const int* rs; const u32* col; u32* out;
    if (bid < nblkA) { xin = x0; rs = rsA; col = colA; out = outA; }
    else { bid -= nblkA; xin = x1; rs = rsB; col = colB; out = outB; }
    int node = bid * 4 + (threadIdx.x >> 6);
    if (node >= n) return;
    node = __builtin_amdgcn_readfirstlane(node);
    int g  = lane >> 3;      // edge group 0..7
    int fl = lane & 7;       // feature octet: features 8fl .. 8fl+7
    int beg = rs[node];
    int dgv = rs[node + 1] - beg;
    int dgm1 = dgv - 1;
    float a0 = 0.f, a1 = 0.f, a2 = 0.f, a3 = 0.f, a4 = 0.f, a5 = 0.f, a6 = 0.f, a7 = 0.f;
    uint4 p = make_uint4(0, 0, 0, 0);
    const uint4* xb = (const uint4*)xin;
    if (dgv > 0) {
        int s = col[beg + imin(g, dgm1)];
        for (int jb = 0; jb < dgv; jb += 8) {
            p = xb[(size_t)s * 8 + fl];
            s = col[beg + imin(jb + 8 + g, dgm1)];   // prefetch next block's col
            a0 += flo(p.x); a1 += fhi(p.x);
            a2 += flo(p.y); a3 += fhi(p.y);
            a4 += flo(p.z); a5 += fhi(p.z);
            a6 += flo(p.w); a7 += fhi(p.w);
        }
    }
    if (g > (dgm1 & 7)) {        // remove clamped-slot overcount (p = row[col[dgm1]])
        a0 -= flo(p.x); a1 -= fhi(p.x);
        a2 -= flo(p.y); a3 -= fhi(p.y);
        a4 -= flo(p.z); a5 -= fhi(p.z);
        a6 -= flo(p.w); a7 -= fhi(p.w);
    }
#pragma unroll
    for (int off = 8; off < 64; off <<= 1) {
        a0 += __shfl_xor(a0, off, 64); a1 += __shfl_xor(a1, off, 64);
        a2 += __shfl_xor(a2, off, 64); a3 += __shfl_xor(a3, off, 64);
        a4 += __shfl_xor(a4, off, 64); a5 += __shfl_xor(a5, off, 64);
        a6 += __shfl_xor(a6, off, 64); a7 += __shfl_xor(a7, off, 64);
    }
    if (g == 0) {
        float inv = __builtin_amdgcn_rcpf((float)(dgv > 1 ? dgv : 1));
        uint4 r;
        r.x = pack2(a0 * inv, a1 * inv);
        r.y = pack2(a2 * inv, a3 * inv);
        r.z = pack2(a4 * inv, a5 * inv);
        r.w = pack2(a6 * inv, a7 * inv);
        ((uint4*)out)[(size_t)node * 8 + fl] = r;
    }
}

// ---- user mix via MFMA: one wave = 16 users, K=128 (sbuf||tbuf), 64 outputs ----
__global__ __launch_bounds__(256) void mix_mfma(u16* __restrict__ sbuf, u16* __restrict__ tbuf,
        const u16* __restrict__ wb /*[64][128] bf16*/, const float* __restrict__ bias, int nu) {
    int lane = threadIdx.x & 63;
    int wv = threadIdx.x >> 6;
    int m = lane & 15, q = lane >> 4;
    int ubase = blockIdx.x * 64 + wv * 16;
    int ul = ubase + m;
    int usafe = ul < nu ? ul : nu - 1;
    const bf16x8* srow = (const bf16x8*)(sbuf + (size_t)usafe * 64);
    const bf16x8* trow = (const bf16x8*)(tbuf + (size_t)usafe * 64);
    bf16x8 a0 = srow[q];
    bf16x8 a1 = srow[4 + q];
    bf16x8 a2 = trow[q];
    bf16x8 a3 = trow[4 + q];
    f32x4 accv[4];
#pragma unroll
    for (int t = 0; t < 4; ++t) { accv[t].x = accv[t].y = accv[t].z = accv[t].w = 0.f; }
#pragma unroll
    for (int t = 0; t < 4; ++t) {
        const u16* wd = wb + (size_t)(t * 16 + m) * 128;
        accv[t] = __builtin_amdgcn_mfma_f32_16x16x32_bf16(a0, *(const bf16x8*)(wd + q * 8), accv[t], 0, 0, 0);
        accv[t] = __builtin_amdgcn_mfma_f32_16x16x32_bf16(a1, *(const bf16x8*)(wd + 32 + q * 8), accv[t], 0, 0, 0);
        accv[t] = __builtin_amdgcn_mfma_f32_16x16x32_bf16(a2, *(const bf16x8*)(wd + 64 + q * 8), accv[t], 0, 0, 0);
        accv[t] = __builtin_amdgcn_mfma_f32_16x16x32_bf16(a3, *(const bf16x8*)(wd + 96 + q * 8), accv[t], 0, 0, 0);
    }
    int urow = ubase + q * 4;
#pragma unroll
    for (int t = 0; t < 4; ++t) {
        float bv = bias[t * 16 + m];
#pragma unroll
        for (int r = 0; r < 4; ++r) {
            int uu = urow + r;
            if (uu < nu) {
                u16 h = f2bf(accv[t][r] + bv);
                sbuf[(size_t)uu * 64 + t * 16 + m] = h;
                tbuf[(size_t)uu * 64 + t * 16 + m] = h;
            }
        }
    }
}

// ---- standalone final predictor ----
__global__ __launch_bounds__(256) void predl_kernel(const u16* __restrict__ xb,
        const int* __restrict__ l0, const int* __restrict__ l1,
        const float* __restrict__ pw, int ofA, int ofB,
        float* __restrict__ acc, int nl,
        const float* __restrict__ pb, float* __restrict__ out) {
    int li = blockIdx.x * 4 + (threadIdx.x >> 6);
    if (li >= nl) return;
    li = __builtin_amdgcn_readfirstlane(li);
    int lane = threadIdx.x & 63;
    int u = l0[li], v = l1[li];
    float s = pw[ofA + lane] * bf2f(xb[(size_t)u * 64 + lane])
            + pw[ofB + lane] * bf2f(xb[(size_t)v * 64 + lane]);
#pragma unroll
    for (int off = 32; off > 0; off >>= 1) s += __shfl_xor(s, off, 64);
    if (lane == 0) {
        float t = acc[li] + s + pb[0];
        t = t > 0.f ? t : 0.01f * t;
        out[li] = 1.f / (1.f + expf(-t));
    }
}

extern "C" void kernel_launch(void* const* d_in, const int* in_sizes, int n_in,
                              void* d_out, int out_size, void* d_ws, size_t ws_size,
                              hipStream_t stream) {
    const int*   se  = (const int*)d_in[0];   // [2,E] src then dst
    const int*   te  = (const int*)d_in[1];
    const int*   lk  = (const int*)d_in[2];   // [2,NLINK]
    const float* emb = (const float*)d_in[3]; // [N,64]
    const float* mw  = (const float*)d_in[4]; // [3,64,128]
    const float* mb  = (const float*)d_in[5]; // [3,64]
    const float* pw  = (const float*)d_in[6]; // [1,512]
    const float* pb  = (const float*)d_in[7]; // [1]
    float* out = (float*)d_out;

    const int E  = in_sizes[0] / 2;
    const int NL = in_sizes[2] / 2;
    const int N  = in_sizes[3] / 64;
    const int U  = 100000;
    const int NB = (N + BWIDTH - 1) >> BSHIFT;   // 391

    char* p = (char*)d_ws;
    auto alloc = [&](size_t bytes) -> char* {
        char* r = p;
        p += (bytes + 255) & ~(size_t)255;
        return r;
    };
    u32* A     = (u32*)alloc((size_t)N * 32 * 4);   // bf16 node buf (25.6MB)
    u32* B     = (u32*)alloc((size_t)N * 32 * 4);
    u32* C     = (u32*)alloc((size_t)N * 32 * 4);   // D1: bf16(emb); later t-chain/s-chain
    u32* col_s = (u32*)alloc((size_t)E * 4);        // bin -> in-place sorted col
    u32* col_t = (u32*)alloc((size_t)E * 4);
    int* rs_s  = (int*)alloc((size_t)(N + 1) * 4);
    int* rs_t  = (int*)alloc((size_t)(N + 1) * 4);
    float* acc = (float*)alloc((size_t)NL * 4);
    int* gcnt2 = (int*)alloc(2 * BWIDTH * 4);
    int* bbase_s = (int*)alloc((BWIDTH + 1) * 4);
    int* bbase_t = (int*)alloc((BWIDTH + 1) * 4);
    int* cur2  = (int*)alloc(2 * BWIDTH * 4);
    u16* mwb   = (u16*)alloc(3 * 64 * 128 * 2);

    hipMemsetAsync(gcnt2, 0, 2 * BWIDTH * 4, stream);

    const int NHIST = (E + HCHUNK - 1) / HCHUNK;     // 367
    const int NBIN  = (E + BCHUNK - 1) / BCHUNK;     // 184
    const int NWPREP = 96;
    const int NCONV = (N * 64 + 1023) / 1024;        // 12500
    const int GA    = (N + 3) / 4;                   // 50000
    const int GAU   = (U + 3) / 4;                   // 25000 (layer-3 t-agg: users only)
    const int GP    = (NL + 3) / 4;                  // 25000
    const int GM    = (U + 63) / 64;                 // 1563

    // D1: hist both + W prep + emb->bf16 into C
    prep_hist<<<2 * NHIST + NWPREP + NCONV, 256, 0, stream>>>(
        se + E, te + E, E, gcnt2, mw, mwb, emb, C, N * 64, NHIST, NWPREP);
    // D2: parallel bucket scans + pred0
    scan_pred0<<<2 + GP, 256, 0, stream>>>(gcnt2, NB, bbase_s, bbase_t, cur2, rs_s, rs_t,
                                           N, emb, lk, lk + NL, pw, acc, NL);
    // D3: bin both
    bin2_kernel<<<2 * NBIN, 256, 0, stream>>>(se, se + E, te, te + E, E, cur2, col_s, col_t, NBIN);
    // D4: sort both
    sort2_kernel<<<2 * NB, 256, 0, stream>>>(col_s, col_t, bbase_s, bbase_t, rs_s, rs_t, N, NB);

    // D5: layer-1 agg, both lists from bf16(emb)=C -> A (s), B (t)
    aggp_kernel<<<2 * GA, 256, 0, stream>>>(
        C, rs_s, col_s, A, GA, C, rs_t, col_t, B, GA, N,
        (const u16*)nullptr, nullptr, nullptr, nullptr, 0, 0, nullptr, 0, 0);
    // D6: mix1 (A,B user rows)
    mix_mfma<<<GM, 256, 0, stream>>>((u16*)A, (u16*)B, mwb + 0 * 8192, mb + 0 * 64, U);
    // D7: predl1(A) + agg_s L2: A -> C
    aggp_kernel<<<GP + GA, 256, 0, stream>>>(
        A, rs_s, col_s, C, GA, nullptr, nullptr, nullptr, nullptr, 0, N,
        (const u16*)A, lk, lk + NL, pw, 64, 320, acc, NL, GP);
    // D8: agg_t L2: B -> A
    aggp_kernel<<<GA, 256, 0, stream>>>(
        B, rs_t, col_t, A, GA, nullptr, nullptr, nullptr, nullptr, 0, N,
        (const u16*)nullptr, nullptr, nullptr, nullptr, 0, 0, nullptr, 0, 0);
    // D9: mix2 (C = s-chain, A = t-chain)
    mix_mfma<<<GM, 256, 0, stream>>>((u16*)C, (u16*)A, mwb + 1 * 8192, mb + 1 * 64, U);
    // D10: predl2(C) + agg_s L3: C -> B
    aggp_kernel<<<GP + GA, 256, 0, stream>>>(
        C, rs_s, col_s, B, GA, nullptr, nullptr, nullptr, nullptr, 0, N,
        (const u16*)C, lk, lk + NL, pw, 128, 384, acc, NL, GP);
    // D11: agg_t L3 (USER dst rows only): A -> C
    aggp_kernel<<<GAU, 256, 0, stream>>>(
        A, rs_t, col_t, C, GAU, nullptr, nullptr, nullptr, nullptr, 0, U,
        (const u16*)nullptr, nullptr, nullptr, nullptr, 0, 0, nullptr, 0, 0);
    // D12: mix3 (B = s-chain, C = t-chain users)
    mix_mfma<<<GM, 256, 0, stream>>>((u16*)B, (u16*)C, mwb + 2 * 8192, mb + 2 * 64, U);
    // D13: final predictor on B (s-chain L3)
    predl_kernel<<<GP, 256, 0, stream>>>((const u16*)B, lk, lk + NL, pw, 192, 448, acc, NL, pb, out);
}

// Round 7
// 771.039 us; speedup vs baseline: 1.1598x; 1.1598x over previous
//
#include <hip/hip_runtime.h>
#include <hip/hip_bf16.h>
#include <math.h>

// N=200000 nodes, U=100000 users, D=64, L=3, E=3,000,000 per edge list, NLINK=100000.
// ws: 3 bf16 node bufs (76.8MB) + 2 bin/col (24MB, sorted in place) + aux ~= 104MB.

typedef unsigned short u16;
typedef unsigned int   u32;
typedef __attribute__((ext_vector_type(8))) short bf16x8;
typedef __attribute__((ext_vector_type(4))) float f32x4;

#define BSHIFT 9                 // 512 nodes per coarse bucket
#define BWIDTH 512
#define BCAP   8192              // LDS staging per sort bucket
#define OVF    8                 // +2048 entries of per-thread register headroom
#define HCHUNK 8192              // edges per hist block
#define BCHUNK 16384             // edges per bin block

__device__ __forceinline__ float bf2f(u16 v) {
    u32 x = ((u32)v) << 16;
    return __builtin_bit_cast(float, x);
}
__device__ __forceinline__ u16 f2bf(float f) {
    u32 x = __builtin_bit_cast(u32, f);
    u32 r = x + 0x7fffu + ((x >> 16) & 1u);   // round-to-nearest-even
    return (u16)(r >> 16);
}
__device__ __forceinline__ u32 pack2(float a, float b) {
    return (u32)f2bf(a) | ((u32)f2bf(b) << 16);
}
__device__ __forceinline__ float flo(u32 p) { return __builtin_bit_cast(float, p << 16); }
__device__ __forceinline__ float fhi(u32 p) { return __builtin_bit_cast(float, p & 0xffff0000u); }
__device__ __forceinline__ int imin(int a, int b) { return a < b ? a : b; }

// ---- D1: fused hist(s) + hist(t) + W->bf16 prep + emb->bf16 staging ----
__global__ __launch_bounds__(256) void prep_hist(const int* __restrict__ sdst,
        const int* __restrict__ tdst, int e, int* __restrict__ gcnt2,
        const float* __restrict__ mw, u16* __restrict__ mwb,
        const float* __restrict__ emb, u32* __restrict__ embb, int nelem,
        int nhist, int nwprep) {
    __shared__ int lcnt[BWIDTH];
    int bid = blockIdx.x, tid = threadIdx.x;
    if (bid < 2 * nhist) {
        const int* dst = (bid < nhist) ? sdst : tdst;
        int* gcnt = gcnt2 + ((bid < nhist) ? 0 : BWIDTH);
        int cb = (bid < nhist) ? bid : bid - nhist;
        for (int i = tid; i < BWIDTH; i += 256) lcnt[i] = 0;
        __syncthreads();
        int base = cb * HCHUNK, end = imin(base + HCHUNK, e);
        for (int i = base + tid; i < end; i += 256)
            atomicAdd(&lcnt[(u32)dst[i] >> BSHIFT], 1);
        __syncthreads();
        for (int i = tid; i < BWIDTH; i += 256)
            if (lcnt[i]) atomicAdd(&gcnt[i], lcnt[i]);
    } else if (bid < 2 * nhist + nwprep) {
        int idx = (bid - 2 * nhist) * 256 + tid;
        if (idx < 3 * 64 * 128) mwb[idx] = f2bf(mw[idx]);
    } else {
        int idx = (bid - 2 * nhist - nwprep) * 1024 + tid * 4;   // 4 floats / thread
        if (idx < nelem) {
            float4 v = *(const float4*)(emb + idx);
            uint2 r;
            r.x = pack2(v.x, v.y);
            r.y = pack2(v.z, v.w);
            *(uint2*)(embb + (idx >> 1)) = r;
        }
    }
}

// ---- D2: parallel bucket scans (2 blocks) + pred0 (layer-0 term, fp32 emb) ----
__global__ __launch_bounds__(256) void scan_pred0(const int* __restrict__ gcnt2, int nb,
        int* __restrict__ bbase_s, int* __restrict__ bbase_t, int* __restrict__ cur2,
        int* __restrict__ rs_s, int* __restrict__ rs_t, int n,
        const float* __restrict__ emb, const int* __restrict__ l0, const int* __restrict__ l1,
        const float* __restrict__ pw, float* __restrict__ acc, int nl) {
    int bid = blockIdx.x;
    int tid = threadIdx.x;
    if (bid < 2) {
        __shared__ int part[256];
        const int* g = gcnt2 + bid * BWIDTH;
        int* bb = bid ? bbase_t : bbase_s;
        int* cu = cur2 + bid * BWIDTH;
        int* rs = bid ? rs_t : rs_s;
        int i0 = tid * 2;
        int c0 = g[i0], c1 = g[i0 + 1];
        int s = c0 + c1;
        part[tid] = s;
        __syncthreads();
        for (int off = 1; off < 256; off <<= 1) {
            int t = (tid >= off) ? part[tid - off] : 0;
            __syncthreads();
            part[tid] += t;
            __syncthreads();
        }
        int excl = part[tid] - s;
        if (i0 <= nb)     { bb[i0] = excl; }
        if (i0 + 1 <= nb) { bb[i0 + 1] = excl + c0; }
        if (i0 < nb)      cu[i0] = excl;
        if (i0 + 1 < nb)  cu[i0 + 1] = excl + c0;
        if (tid == 255)   rs[n] = part[255];
        return;
    }
    int li = (bid - 2) * 4 + (tid >> 6);
    if (li >= nl) return;
    li = __builtin_amdgcn_readfirstlane(li);
    int lane = tid & 63;
    int u = l0[li], v = l1[li];
    float s = pw[lane] * emb[(size_t)u * 64 + lane] + pw[256 + lane] * emb[(size_t)v * 64 + lane];
#pragma unroll
    for (int off = 32; off > 0; off >>= 1) s += __shfl_xor(s, off, 64);
    if (lane == 0) acc[li] = s;
}

// ---- D3: fused binning (both lists) ----
__global__ __launch_bounds__(256) void bin2_kernel(const int* __restrict__ ssrc,
        const int* __restrict__ sdst, const int* __restrict__ tsrc, const int* __restrict__ tdst,
        int e, int* __restrict__ cur2, u32* __restrict__ bin_s, u32* __restrict__ bin_t,
        int nbin) {
    __shared__ int lcnt[BWIDTH];
    __shared__ int lbase[BWIDTH];
    int bid = blockIdx.x, tid = threadIdx.x;
    const int* src; const int* dst; int* cursor; u32* bin; int cb;
    if (bid < nbin) { src = ssrc; dst = sdst; cursor = cur2; bin = bin_s; cb = bid; }
    else { src = tsrc; dst = tdst; cursor = cur2 + BWIDTH; bin = bin_t; cb = bid - nbin; }
    for (int i = tid; i < BWIDTH; i += 256) lcnt[i] = 0;
    __syncthreads();
    int base = cb * BCHUNK, end = imin(base + BCHUNK, e);
    for (int i = base + tid; i < end; i += 256)
        atomicAdd(&lcnt[(u32)dst[i] >> BSHIFT], 1);
    __syncthreads();
    for (int i = tid; i < BWIDTH; i += 256) {
        int c = lcnt[i];
        lbase[i] = c ? atomicAdd(&cursor[i], c) : 0;
        lcnt[i] = 0;
    }
    __syncthreads();
    for (int i = base + tid; i < end; i += 256) {
        int d = dst[i];
        int b = (u32)d >> BSHIFT;
        int pos = lbase[b] + atomicAdd(&lcnt[b], 1);
        bin[pos] = (u32)src[i] | ((u32)(d & (BWIDTH - 1)) << 18);   // src < 2^18
    }
}

// ---- D4: fused per-bucket counting sort (both lists), in place ----
__global__ __launch_bounds__(256) void sort2_kernel(u32* __restrict__ bin_s, u32* __restrict__ bin_t,
        const int* __restrict__ bbase_s, const int* __restrict__ bbase_t,
        int* __restrict__ rs_s, int* __restrict__ rs_t, int n, int nb) {
    __shared__ u32 ent[BCAP];
    __shared__ int cnt[BWIDTH];
    __shared__ int part[256];
    int bid = blockIdx.x, tid = threadIdx.x;
    u32* bin; const int* bbase; int* rowstart; int b;
    if (bid < nb) { bin = bin_s; bbase = bbase_s; rowstart = rs_s; b = bid; }
    else { bin = bin_t; bbase = bbase_t; rowstart = rs_t; b = bid - nb; }
    int beg = bbase[b], end = bbase[b + 1];
    int sz = end - beg;
    for (int i = tid; i < BWIDTH; i += 256) cnt[i] = 0;
    __syncthreads();
    u32 ovf[OVF];
    for (int i = tid; i < sz; i += 256) {
        u32 v = bin[beg + i];
        if (i < BCAP) ent[i] = v;
        else { int k = (i - BCAP) >> 8; if (k < OVF) ovf[k] = v; }
        atomicAdd(&cnt[v >> 18], 1);
    }
    __syncthreads();
    int l0 = tid * 2;
    int c0 = cnt[l0], c1 = cnt[l0 + 1];
    int s = c0 + c1;
    part[tid] = s;
    __syncthreads();
    for (int off = 1; off < 256; off <<= 1) {
        int t = (tid >= off) ? part[tid - off] : 0;
        __syncthreads();
        part[tid] += t;
        __syncthreads();
    }
    int excl = part[tid] - s;
    int node = (b << BSHIFT) + l0;
    if (node < n)     rowstart[node]     = beg + excl;
    if (node + 1 < n) rowstart[node + 1] = beg + excl + c0;
    cnt[l0]     = excl;
    cnt[l0 + 1] = excl + c0;
    __syncthreads();
    for (int i = tid; i < sz; i += 256) {
        u32 v;
        if (i < BCAP) v = ent[i];
        else { int k = (i - BCAP) >> 8; v = (k < OVF) ? ovf[k] : bin[beg + i]; }
        int pos = atomicAdd(&cnt[v >> 18], 1);
        bin[beg + pos] = v & 0x3FFFFu;
    }
}

// ---- mean aggregation (bf16 in/out) + optional fused predictor blocks ----
// TWO nodes per wave (32 lanes each); 8 lanes/edge (uint4 = 16B), 4 edge groups,
// 8-slot blocks with TWO row loads in flight per node (slots g and g+4) -> 4
// independent gathers per wave. No per-slot masks: only the last per-lane
// iteration can clamp (jb+7 <= dgm1 for earlier blocks), so clamped slots
// overcount row[col[dgm1]], removed by one conditional subtract after the loop.
__global__ __launch_bounds__(256) void aggp_kernel(
        const u32* __restrict__ x0, const int* __restrict__ rsA, const u32* __restrict__ colA,
        u32* __restrict__ outA, int nblkA,
        const u32* __restrict__ x1, const int* __restrict__ rsB, const u32* __restrict__ colB,
        u32* __restrict__ outB, int nblkB, int n,
        const u16* __restrict__ px, const int* __restrict__ l0, const int* __restrict__ l1,
        const float* __restrict__ pw, int ofA, int ofB, float* __restrict__ acc, int nl,
        int npred) {
    int bid = blockIdx.x;
    int lane = threadIdx.x & 63;
    if (bid < npred) {
        int li = bid * 4 + (threadIdx.x >> 6);
        if (li >= nl) return;
        li = __builtin_amdgcn_readfirstlane(li);
        int u = l0[li], v = l1[li];
        float s = pw[ofA + lane] * bf2f(px[(size_t)u * 64 + lane])
                + pw[ofB + lane] * bf2f(px[(size_t)v * 64 + lane]);
#pragma unroll
        for (int off = 32; off > 0; off >>= 1) s += __shfl_xor(s, off, 64);
        if (lane == 0) acc[li] += s;
        return;
    }
    bid -= npred;
    const u32* xin; const int* rs; const u32* col; u32* out;
    if (bid < nblkA) { xin = x0; rs = rsA; col = colA; out = outA; }
    else { bid -= nblkA; xin = x1; rs = rsB; col = colB; out = outB; }
    int node = bid * 8 + (threadIdx.x >> 5);   // one node per 32-lane half-wave
    if (node >= n) return;
    int fl = lane & 7;           // feature octet: features 8fl .. 8fl+7
    int g  = (lane >> 3) & 3;    // edge group 0..3 within the half-wave
    int beg = rs[node];
    int dgv = rs[node + 1] - beg;
    int dgm1 = dgv - 1;
    float a0 = 0.f, a1 = 0.f, a2 = 0.f, a3 = 0.f, a4 = 0.f, a5 = 0.f, a6 = 0.f, a7 = 0.f;
    uint4 p0 = make_uint4(0, 0, 0, 0), p1 = make_uint4(0, 0, 0, 0);
    const uint4* xb = (const uint4*)xin;
    if (dgv > 0) {
        int s0 = col[beg + imin(g, dgm1)];
        int s1 = col[beg + imin(g + 4, dgm1)];
        for (int jb = 0; jb < dgv; jb += 8) {
            p0 = xb[(size_t)s0 * 8 + fl];
            p1 = xb[(size_t)s1 * 8 + fl];
            int nj = jb + 8 + g;
            s0 = col[beg + imin(nj, dgm1)];       // prefetch next block's cols
            s1 = col[beg + imin(nj + 4, dgm1)];
            a0 += flo(p0.x) + flo(p1.x); a1 += fhi(p0.x) + fhi(p1.x);
            a2 += flo(p0.y) + flo(p1.y); a3 += fhi(p0.y) + fhi(p1.y);
            a4 += flo(p0.z) + flo(p1.z); a5 += fhi(p0.z) + fhi(p1.z);
            a6 += flo(p0.w) + flo(p1.w); a7 += fhi(p0.w) + fhi(p1.w);
        }
        int jbl = (dgm1 >> 3) << 3;               // last iteration's block base
        if (jbl + g > dgm1) {                     // p0 slot clamped -> remove
            a0 -= flo(p0.x); a1 -= fhi(p0.x);
            a2 -= flo(p0.y); a3 -= fhi(p0.y);
            a4 -= flo(p0.z); a5 -= fhi(p0.z);
            a6 -= flo(p0.w); a7 -= fhi(p0.w);
        }
        if (jbl + 4 + g > dgm1) {                 // p1 slot clamped -> remove
            a0 -= flo(p1.x); a1 -= fhi(p1.x);
            a2 -= flo(p1.y); a3 -= fhi(p1.y);
            a4 -= flo(p1.z); a5 -= fhi(p1.z);
            a6 -= flo(p1.w); a7 -= fhi(p1.w);
        }
    }
#pragma unroll
    for (int off = 8; off <= 16; off <<= 1) {     // reduce over 4 edge groups
        a0 += __shfl_xor(a0, off, 64); a1 += __shfl_xor(a1, off, 64);
        a2 += __shfl_xor(a2, off, 64); a3 += __shfl_xor(a3, off, 64);
        a4 += __shfl_xor(a4, off, 64); a5 += __shfl_xor(a5, off, 64);
        a6 += __shfl_xor(a6, off, 64); a7 += __shfl_xor(a7, off, 64);
    }
    if (g == 0) {
        float inv = __builtin_amdgcn_rcpf((float)(dgv > 1 ? dgv : 1));
        uint4 r;
        r.x = pack2(a0 * inv, a1 * inv);
        r.y = pack2(a2 * inv, a3 * inv);
        r.z = pack2(a4 * inv, a5 * inv);
        r.w = pack2(a6 * inv, a7 * inv);
        ((uint4*)out)[(size_t)node * 8 + fl] = r;
    }
}

// ---- user mix via MFMA: one wave = 16 users, K=128 (sbuf||tbuf), 64 outputs ----
__global__ __launch_bounds__(256) void mix_mfma(u16* __restrict__ sbuf, u16* __restrict__ tbuf,
        const u16* __restrict__ wb /*[64][128] bf16*/, const float* __restrict__ bias, int nu) {
    int lane = threadIdx.x & 63;
    int wv = threadIdx.x >> 6;
    int m = lane & 15, q = lane >> 4;
    int ubase = blockIdx.x * 64 + wv * 16;
    int ul = ubase + m;
    int usafe = ul < nu ? ul : nu - 1;
    const bf16x8* srow = (const bf16x8*)(sbuf + (size_t)usafe * 64);
    const bf16x8* trow = (const bf16x8*)(tbuf + (size_t)usafe * 64);
    bf16x8 a0 = srow[q];
    bf16x8 a1 = srow[4 + q];
    bf16x8 a2 = trow[q];
    bf16x8 a3 = trow[4 + q];
    f32x4 accv[4];
#pragma unroll
    for (int t = 0; t < 4; ++t) { accv[t].x = accv[t].y = accv[t].z = accv[t].w = 0.f; }
#pragma unroll
    for (int t = 0; t < 4; ++t) {
        const u16* wd = wb + (size_t)(t * 16 + m) * 128;
        accv[t] = __builtin_amdgcn_mfma_f32_16x16x32_bf16(a0, *(const bf16x8*)(wd + q * 8), accv[t], 0, 0, 0);
        accv[t] = __builtin_amdgcn_mfma_f32_16x16x32_bf16(a1, *(const bf16x8*)(wd + 32 + q * 8), accv[t], 0, 0, 0);
        accv[t] = __builtin_amdgcn_mfma_f32_16x16x32_bf16(a2, *(const bf16x8*)(wd + 64 + q * 8), accv[t], 0, 0, 0);
        accv[t] = __builtin_amdgcn_mfma_f32_16x16x32_bf16(a3, *(const bf16x8*)(wd + 96 + q * 8), accv[t], 0, 0, 0);
    }
    int urow = ubase + q * 4;
#pragma unroll
    for (int t = 0; t < 4; ++t) {
        float bv = bias[t * 16 + m];
#pragma unroll
        for (int r = 0; r < 4; ++r) {
            int uu = urow + r;
            if (uu < nu) {
                u16 h = f2bf(accv[t][r] + bv);
                sbuf[(size_t)uu * 64 + t * 16 + m] = h;
                tbuf[(size_t)uu * 64 + t * 16 + m] = h;
            }
        }
    }
}

// ---- standalone final predictor ----
__global__ __launch_bounds__(256) void predl_kernel(const u16* __restrict__ xb,
        const int* __restrict__ l0, const int* __restrict__ l1,
        const float* __restrict__ pw, int ofA, int ofB,
        float* __restrict__ acc, int nl,
        const float* __restrict__ pb, float* __restrict__ out) {
    int li = blockIdx.x * 4 + (threadIdx.x >> 6);
    if (li >= nl) return;
    li = __builtin_amdgcn_readfirstlane(li);
    int lane = threadIdx.x & 63;
    int u = l0[li], v = l1[li];
    float s = pw[ofA + lane] * bf2f(xb[(size_t)u * 64 + lane])
            + pw[ofB + lane] * bf2f(xb[(size_t)v * 64 + lane]);
#pragma unroll
    for (int off = 32; off > 0; off >>= 1) s += __shfl_xor(s, off, 64);
    if (lane == 0) {
        float t = acc[li] + s + pb[0];
        t = t > 0.f ? t : 0.01f * t;
        out[li] = 1.f / (1.f + expf(-t));
    }
}

extern "C" void kernel_launch(void* const* d_in, const int* in_sizes, int n_in,
                              void* d_out, int out_size, void* d_ws, size_t ws_size,
                              hipStream_t stream) {
    const int*   se  = (const int*)d_in[0];   // [2,E] src then dst
    const int*   te  = (const int*)d_in[1];
    const int*   lk  = (const int*)d_in[2];   // [2,NLINK]
    const float* emb = (const float*)d_in[3]; // [N,64]
    const float* mw  = (const float*)d_in[4]; // [3,64,128]
    const float* mb  = (const float*)d_in[5]; // [3,64]
    const float* pw  = (const float*)d_in[6]; // [1,512]
    const float* pb  = (const float*)d_in[7]; // [1]
    float* out = (float*)d_out;

    const int E  = in_sizes[0] / 2;
    const int NL = in_sizes[2] / 2;
    const int N  = in_sizes[3] / 64;
    const int U  = 100000;
    const int NB = (N + BWIDTH - 1) >> BSHIFT;   // 391

    char* p = (char*)d_ws;
    auto alloc = [&](size_t bytes) -> char* {
        char* r = p;
        p += (bytes + 255) & ~(size_t)255;
        return r;
    };
    u32* A     = (u32*)alloc((size_t)N * 32 * 4);   // bf16 node buf (25.6MB)
    u32* B     = (u32*)alloc((size_t)N * 32 * 4);
    u32* C     = (u32*)alloc((size_t)N * 32 * 4);   // D1: bf16(emb); later t-chain/s-chain
    u32* col_s = (u32*)alloc((size_t)E * 4);        // bin -> in-place sorted col
    u32* col_t = (u32*)alloc((size_t)E * 4);
    int* rs_s  = (int*)alloc((size_t)(N + 1) * 4);
    int* rs_t  = (int*)alloc((size_t)(N + 1) * 4);
    float* acc = (float*)alloc((size_t)NL * 4);
    int* gcnt2 = (int*)alloc(2 * BWIDTH * 4);
    int* bbase_s = (int*)alloc((BWIDTH + 1) * 4);
    int* bbase_t = (int*)alloc((BWIDTH + 1) * 4);
    int* cur2  = (int*)alloc(2 * BWIDTH * 4);
    u16* mwb   = (u16*)alloc(3 * 64 * 128 * 2);

    hipMemsetAsync(gcnt2, 0, 2 * BWIDTH * 4, stream);

    const int NHIST = (E + HCHUNK - 1) / HCHUNK;     // 367
    const int NBIN  = (E + BCHUNK - 1) / BCHUNK;     // 184
    const int NWPREP = 96;
    const int NCONV = (N * 64 + 1023) / 1024;        // 12500
    const int GA    = (N + 7) / 8;                   // 25000 agg blocks (8 nodes/block)
    const int GAU   = (U + 7) / 8;                   // 12500 (layer-3 t-agg: users only)
    const int GP    = (NL + 3) / 4;                  // 25000
    const int GM    = (U + 63) / 64;                 // 1563

    // D1: hist both + W prep + emb->bf16 into C
    prep_hist<<<2 * NHIST + NWPREP + NCONV, 256, 0, stream>>>(
        se + E, te + E, E, gcnt2, mw, mwb, emb, C, N * 64, NHIST, NWPREP);
    // D2: parallel bucket scans + pred0
    scan_pred0<<<2 + GP, 256, 0, stream>>>(gcnt2, NB, bbase_s, bbase_t, cur2, rs_s, rs_t,
                                           N, emb, lk, lk + NL, pw, acc, NL);
    // D3: bin both
    bin2_kernel<<<2 * NBIN, 256, 0, stream>>>(se, se + E, te, te + E, E, cur2, col_s, col_t, NBIN);
    // D4: sort both
    sort2_kernel<<<2 * NB, 256, 0, stream>>>(col_s, col_t, bbase_s, bbase_t, rs_s, rs_t, N, NB);

    // D5: layer-1 agg, both lists from bf16(emb)=C -> A (s), B (t)
    aggp_kernel<<<2 * GA, 256, 0, stream>>>(
        C, rs_s, col_s, A, GA, C, rs_t, col_t, B, GA, N,
        (const u16*)nullptr, nullptr, nullptr, nullptr, 0, 0, nullptr, 0, 0);
    // D6: mix1 (A,B user rows)
    mix_mfma<<<GM, 256, 0, stream>>>((u16*)A, (u16*)B, mwb + 0 * 8192, mb + 0 * 64, U);
    // D7: predl1(A) + agg_s L2: A -> C
    aggp_kernel<<<GP + GA, 256, 0, stream>>>(
        A, rs_s, col_s, C, GA, nullptr, nullptr, nullptr, nullptr, 0, N,
        (const u16*)A, lk, lk + NL, pw, 64, 320, acc, NL, GP);
    // D8: agg_t L2: B -> A
    aggp_kernel<<<GA, 256, 0, stream>>>(
        B, rs_t, col_t, A, GA, nullptr, nullptr, nullptr, nullptr, 0, N,
        (const u16*)nullptr, nullptr, nullptr, nullptr, 0, 0, nullptr, 0, 0);
    // D9: mix2 (C = s-chain, A = t-chain)
    mix_mfma<<<GM, 256, 0, stream>>>((u16*)C, (u16*)A, mwb + 1 * 8192, mb + 1 * 64, U);
    // D10: predl2(C) + agg_s L3: C -> B
    aggp_kernel<<<GP + GA, 256, 0, stream>>>(
        C, rs_s, col_s, B, GA, nullptr, nullptr, nullptr, nullptr, 0, N,
        (const u16*)C, lk, lk + NL, pw, 128, 384, acc, NL, GP);
    // D11: agg_t L3 (USER dst rows only): A -> C
    aggp_kernel<<<GAU, 256, 0, stream>>>(
        A, rs_t, col_t, C, GAU, nullptr, nullptr, nullptr, nullptr, 0, U,
        (const u16*)nullptr, nullptr, nullptr, nullptr, 0, 0, nullptr, 0, 0);
    // D12: mix3 (B = s-chain, C = t-chain users)
    mix_mfma<<<GM, 256, 0, stream>>>((u16*)B, (u16*)C, mwb + 2 * 8192, mb + 2 * 64, U);
    // D13: final predictor on B (s-chain L3)
    predl_kernel<<<GP, 256, 0, stream>>>((const u16*)B, lk, lk + NL, pw, 192, 448, acc, NL, pb, out);
}

// Round 8
// 766.529 us; speedup vs baseline: 1.1666x; 1.0059x over previous
//
#include <hip/hip_runtime.h>
#include <hip/hip_bf16.h>
#include <math.h>

// N=200000 nodes, U=100000 users, D=64, L=3, E=3,000,000 per edge list, NLINK=100000.
// ws: 3 bf16 node bufs (76.8MB) + 2 bin/col (24MB, sorted in place) + aux ~= 104MB.

typedef unsigned short u16;
typedef unsigned int   u32;
typedef __attribute__((ext_vector_type(8))) short bf16x8;
typedef __attribute__((ext_vector_type(4))) float f32x4;

#define BSHIFT 8                 // 256 nodes per coarse bucket
#define NODESB 256               // nodes per bucket
#define NBPAD  1024              // padded bucket-count array (782 used)
#define BCAP   4096              // LDS staging per sort bucket (mean ~3840)
#define OVF    8                 // +2048 entries of per-thread register headroom
#define HCHUNK 8192              // edges per hist block
#define BCHUNK 4096              // edges per bin block (occupancy play)

__device__ __forceinline__ float bf2f(u16 v) {
    u32 x = ((u32)v) << 16;
    return __builtin_bit_cast(float, x);
}
__device__ __forceinline__ u16 f2bf(float f) {
    u32 x = __builtin_bit_cast(u32, f);
    u32 r = x + 0x7fffu + ((x >> 16) & 1u);   // round-to-nearest-even
    return (u16)(r >> 16);
}
__device__ __forceinline__ u32 pack2(float a, float b) {
    return (u32)f2bf(a) | ((u32)f2bf(b) << 16);
}
__device__ __forceinline__ float flo(u32 p) { return __builtin_bit_cast(float, p << 16); }
__device__ __forceinline__ float fhi(u32 p) { return __builtin_bit_cast(float, p & 0xffff0000u); }
__device__ __forceinline__ int imin(int a, int b) { return a < b ? a : b; }

// ---- D1: fused hist(s) + hist(t) + W->bf16 prep + emb->bf16 staging ----
__global__ __launch_bounds__(256) void prep_hist(const int* __restrict__ sdst,
        const int* __restrict__ tdst, int e, int* __restrict__ gcnt2,
        const float* __restrict__ mw, u16* __restrict__ mwb,
        const float* __restrict__ emb, u32* __restrict__ embb, int nelem,
        int nhist, int nwprep) {
    __shared__ int lcnt[NBPAD];
    int bid = blockIdx.x, tid = threadIdx.x;
    if (bid < 2 * nhist) {
        const int* dst = (bid < nhist) ? sdst : tdst;
        int* gcnt = gcnt2 + ((bid < nhist) ? 0 : NBPAD);
        int cb = (bid < nhist) ? bid : bid - nhist;
        for (int i = tid; i < NBPAD; i += 256) lcnt[i] = 0;
        __syncthreads();
        int base = cb * HCHUNK, end = imin(base + HCHUNK, e);
        for (int i = base + tid; i < end; i += 256)
            atomicAdd(&lcnt[(u32)dst[i] >> BSHIFT], 1);
        __syncthreads();
        for (int i = tid; i < NBPAD; i += 256)
            if (lcnt[i]) atomicAdd(&gcnt[i], lcnt[i]);
    } else if (bid < 2 * nhist + nwprep) {
        int idx = (bid - 2 * nhist) * 256 + tid;
        if (idx < 3 * 64 * 128) mwb[idx] = f2bf(mw[idx]);
    } else {
        int idx = (bid - 2 * nhist - nwprep) * 1024 + tid * 4;   // 4 floats / thread
        if (idx < nelem) {
            float4 v = *(const float4*)(emb + idx);
            uint2 r;
            r.x = pack2(v.x, v.y);
            r.y = pack2(v.z, v.w);
            *(uint2*)(embb + (idx >> 1)) = r;
        }
    }
}

// ---- D2: parallel bucket scans (2 blocks, 1024 counts @ 4/thread) + pred0 ----
__global__ __launch_bounds__(256) void scan_pred0(const int* __restrict__ gcnt2, int nb,
        int* __restrict__ bbase_s, int* __restrict__ bbase_t, int* __restrict__ cur2,
        int* __restrict__ rs_s, int* __restrict__ rs_t, int n,
        const float* __restrict__ emb, const int* __restrict__ l0, const int* __restrict__ l1,
        const float* __restrict__ pw, float* __restrict__ acc, int nl) {
    int bid = blockIdx.x;
    int tid = threadIdx.x;
    if (bid < 2) {
        __shared__ int part[256];
        const int* g = gcnt2 + bid * NBPAD;
        int* bb = bid ? bbase_t : bbase_s;
        int* cu = cur2 + bid * NBPAD;
        int* rs = bid ? rs_t : rs_s;
        int i0 = tid * 4;
        int c[4]; int s = 0;
#pragma unroll
        for (int j = 0; j < 4; ++j) { c[j] = g[i0 + j]; s += c[j]; }  // zero beyond nb
        part[tid] = s;
        __syncthreads();
        for (int off = 1; off < 256; off <<= 1) {
            int t = (tid >= off) ? part[tid - off] : 0;
            __syncthreads();
            part[tid] += t;
            __syncthreads();
        }
        int excl = part[tid] - s;
#pragma unroll
        for (int j = 0; j < 4; ++j) {
            int idx = i0 + j;
            if (idx <= nb) bb[idx] = excl;
            if (idx < nb)  cu[idx] = excl;
            excl += c[j];
        }
        if (tid == 255) rs[n] = part[255];
        return;
    }
    int li = (bid - 2) * 4 + (tid >> 6);
    if (li >= nl) return;
    li = __builtin_amdgcn_readfirstlane(li);
    int lane = tid & 63;
    int u = l0[li], v = l1[li];
    float s = pw[lane] * emb[(size_t)u * 64 + lane] + pw[256 + lane] * emb[(size_t)v * 64 + lane];
#pragma unroll
    for (int off = 32; off > 0; off >>= 1) s += __shfl_xor(s, off, 64);
    if (lane == 0) acc[li] = s;
}

// ---- D3: fused binning (both lists), 4096-edge chunks ----
__global__ __launch_bounds__(256) void bin2_kernel(const int* __restrict__ ssrc,
        const int* __restrict__ sdst, const int* __restrict__ tsrc, const int* __restrict__ tdst,
        int e, int* __restrict__ cur2, u32* __restrict__ bin_s, u32* __restrict__ bin_t,
        int nbin) {
    __shared__ int lcnt[NBPAD];
    __shared__ int lbase[NBPAD];
    int bid = blockIdx.x, tid = threadIdx.x;
    const int* src; const int* dst; int* cursor; u32* bin; int cb;
    if (bid < nbin) { src = ssrc; dst = sdst; cursor = cur2; bin = bin_s; cb = bid; }
    else { src = tsrc; dst = tdst; cursor = cur2 + NBPAD; bin = bin_t; cb = bid - nbin; }
    for (int i = tid; i < NBPAD; i += 256) lcnt[i] = 0;
    __syncthreads();
    int base = cb * BCHUNK, end = imin(base + BCHUNK, e);
    for (int i = base + tid; i < end; i += 256)
        atomicAdd(&lcnt[(u32)dst[i] >> BSHIFT], 1);
    __syncthreads();
    for (int i = tid; i < NBPAD; i += 256) {
        int c = lcnt[i];
        lbase[i] = c ? atomicAdd(&cursor[i], c) : 0;
        lcnt[i] = 0;
    }
    __syncthreads();
    for (int i = base + tid; i < end; i += 256) {
        int d = dst[i];
        int b = (u32)d >> BSHIFT;
        int pos = lbase[b] + atomicAdd(&lcnt[b], 1);
        bin[pos] = (u32)src[i] | ((u32)(d & (NODESB - 1)) << 18);   // src < 2^18, local 8b
    }
}

// ---- D4: fused per-bucket counting sort (both lists), in place ----
__global__ __launch_bounds__(256) void sort2_kernel(u32* __restrict__ bin_s, u32* __restrict__ bin_t,
        const int* __restrict__ bbase_s, const int* __restrict__ bbase_t,
        int* __restrict__ rs_s, int* __restrict__ rs_t, int n, int nb) {
    __shared__ u32 ent[BCAP];
    __shared__ int cnt[NODESB];
    __shared__ int part[256];
    int bid = blockIdx.x, tid = threadIdx.x;
    u32* bin; const int* bbase; int* rowstart; int b;
    if (bid < nb) { bin = bin_s; bbase = bbase_s; rowstart = rs_s; b = bid; }
    else { bin = bin_t; bbase = bbase_t; rowstart = rs_t; b = bid - nb; }
    int beg = bbase[b], end = bbase[b + 1];
    int sz = end - beg;
    cnt[tid] = 0;
    __syncthreads();
    u32 ovf[OVF];
    for (int i = tid; i < sz; i += 256) {
        u32 v = bin[beg + i];
        if (i < BCAP) ent[i] = v;
        else { int k = (i - BCAP) >> 8; if (k < OVF) ovf[k] = v; }
        atomicAdd(&cnt[v >> 18], 1);
    }
    __syncthreads();
    int c = cnt[tid];
    part[tid] = c;
    __syncthreads();
    for (int off = 1; off < 256; off <<= 1) {
        int t = (tid >= off) ? part[tid - off] : 0;
        __syncthreads();
        part[tid] += t;
        __syncthreads();
    }
    int excl = part[tid] - c;
    int node = (b << BSHIFT) + tid;
    if (node < n) rowstart[node] = beg + excl;
    cnt[tid] = excl;             // running cursor for scatter phase
    __syncthreads();
    for (int i = tid; i < sz; i += 256) {
        u32 v;
        if (i < BCAP) v = ent[i];
        else { int k = (i - BCAP) >> 8; v = (k < OVF) ? ovf[k] : bin[beg + i]; }
        int pos = atomicAdd(&cnt[v >> 18], 1);
        bin[beg + pos] = v & 0x3FFFFu;
    }
}

// ---- mean aggregation (bf16 in/out) + optional fused predictor blocks ----
// TWO nodes per wave (32 lanes each); 8 lanes/edge (uint4 = 16B), 4 edge groups,
// 8-slot blocks with TWO row loads in flight per node -> 4 gathers/wave in flight.
__global__ __launch_bounds__(256) void aggp_kernel(
        const u32* __restrict__ x0, const int* __restrict__ rsA, const u32* __restrict__ colA,
        u32* __restrict__ outA, int nblkA,
        const u32* __restrict__ x1, const int* __restrict__ rsB, const u32* __restrict__ colB,
        u32* __restrict__ outB, int nblkB, int n,
        const u16* __restrict__ px, const int* __restrict__ l0, const int* __restrict__ l1,
        const float* __restrict__ pw, int ofA, int ofB, float* __restrict__ acc, int nl,
        int npred) {
    int bid = blockIdx.x;
    int lane = threadIdx.x & 63;
    if (bid < npred) {
        int li = bid * 4 + (threadIdx.x >> 6);
        if (li >= nl) return;
        li = __builtin_amdgcn_readfirstlane(li);
        int u = l0[li], v = l1[li];
        float s = pw[ofA + lane] * bf2f(px[(size_t)u * 64 + lane])
                + pw[ofB + lane] * bf2f(px[(size_t)v * 64 + lane]);
#pragma unroll
        for (int off = 32; off > 0; off >>= 1) s += __shfl_xor(s, off, 64);
        if (lane == 0) acc[li] += s;
        return;
    }
    bid -= npred;
    const u32* xin; const int* rs; const u32* col; u32* out;
    if (bid < nblkA) { xin = x0; rs = rsA; col = colA; out = outA; }
    else { bid -= nblkA; xin = x1; rs = rsB; col = colB; out = outB; }
    int node = bid * 8 + (threadIdx.x >> 5);   // one node per 32-lane half-wave
    if (node >= n) return;
    int fl = lane & 7;           // feature octet: features 8fl .. 8fl+7
    int g  = (lane >> 3) & 3;    // edge group 0..3 within the half-wave
    int beg = rs[node];
    int dgv = rs[node + 1] - beg;
    int dgm1 = dgv - 1;
    float a0 = 0.f, a1 = 0.f, a2 = 0.f, a3 = 0.f, a4 = 0.f, a5 = 0.f, a6 = 0.f, a7 = 0.f;
    uint4 p0 = make_uint4(0, 0, 0, 0), p1 = make_uint4(0, 0, 0, 0);
    const uint4* xb = (const uint4*)xin;
    if (dgv > 0) {
        int s0 = col[beg + imin(g, dgm1)];
        int s1 = col[beg + imin(g + 4, dgm1)];
        for (int jb = 0; jb < dgv; jb += 8) {
            p0 = xb[(size_t)s0 * 8 + fl];
            p1 = xb[(size_t)s1 * 8 + fl];
            int nj = jb + 8 + g;
            s0 = col[beg + imin(nj, dgm1)];       // prefetch next block's cols
            s1 = col[beg + imin(nj + 4, dgm1)];
            a0 += flo(p0.x) + flo(p1.x); a1 += fhi(p0.x) + fhi(p1.x);
            a2 += flo(p0.y) + flo(p1.y); a3 += fhi(p0.y) + fhi(p1.y);
            a4 += flo(p0.z) + flo(p1.z); a5 += fhi(p0.z) + fhi(p1.z);
            a6 += flo(p0.w) + flo(p1.w); a7 += fhi(p0.w) + fhi(p1.w);
        }
        int jbl = (dgm1 >> 3) << 3;               // last iteration's block base
        if (jbl + g > dgm1) {                     // p0 slot clamped -> remove
            a0 -= flo(p0.x); a1 -= fhi(p0.x);
            a2 -= flo(p0.y); a3 -= fhi(p0.y);
            a4 -= flo(p0.z); a5 -= fhi(p0.z);
            a6 -= flo(p0.w); a7 -= fhi(p0.w);
        }
        if (jbl + 4 + g > dgm1) {                 // p1 slot clamped -> remove
            a0 -= flo(p1.x); a1 -= fhi(p1.x);
            a2 -= flo(p1.y); a3 -= fhi(p1.y);
            a4 -= flo(p1.z); a5 -= fhi(p1.z);
            a6 -= flo(p1.w); a7 -= fhi(p1.w);
        }
    }
#pragma unroll
    for (int off = 8; off <= 16; off <<= 1) {     // reduce over 4 edge groups
        a0 += __shfl_xor(a0, off, 64); a1 += __shfl_xor(a1, off, 64);
        a2 += __shfl_xor(a2, off, 64); a3 += __shfl_xor(a3, off, 64);
        a4 += __shfl_xor(a4, off, 64); a5 += __shfl_xor(a5, off, 64);
        a6 += __shfl_xor(a6, off, 64); a7 += __shfl_xor(a7, off, 64);
    }
    if (g == 0) {
        float inv = __builtin_amdgcn_rcpf((float)(dgv > 1 ? dgv : 1));
        uint4 r;
        r.x = pack2(a0 * inv, a1 * inv);
        r.y = pack2(a2 * inv, a3 * inv);
        r.z = pack2(a4 * inv, a5 * inv);
        r.w = pack2(a6 * inv, a7 * inv);
        ((uint4*)out)[(size_t)node * 8 + fl] = r;
    }
}

// ---- user mix via MFMA: one wave = 16 users, K=128 (sbuf||tbuf), 64 outputs ----
__global__ __launch_bounds__(256) void mix_mfma(u16* __restrict__ sbuf, u16* __restrict__ tbuf,
        const u16* __restrict__ wb /*[64][128] bf16*/, const float* __restrict__ bias, int nu) {
    int lane = threadIdx.x & 63;
    int wv = threadIdx.x >> 6;
    int m = lane & 15, q = lane >> 4;
    int ubase = blockIdx.x * 64 + wv * 16;
    int ul = ubase + m;
    int usafe = ul < nu ? ul : nu - 1;
    const bf16x8* srow = (const bf16x8*)(sbuf + (size_t)usafe * 64);
    const bf16x8* trow = (const bf16x8*)(tbuf + (size_t)usafe * 64);
    bf16x8 a0 = srow[q];
    bf16x8 a1 = srow[4 + q];
    bf16x8 a2 = trow[q];
    bf16x8 a3 = trow[4 + q];
    f32x4 accv[4];
#pragma unroll
    for (int t = 0; t < 4; ++t) { accv[t].x = accv[t].y = accv[t].z = accv[t].w = 0.f; }
#pragma unroll
    for (int t = 0; t < 4; ++t) {
        const u16* wd = wb + (size_t)(t * 16 + m) * 128;
        accv[t] = __builtin_amdgcn_mfma_f32_16x16x32_bf16(a0, *(const bf16x8*)(wd + q * 8), accv[t], 0, 0, 0);
        accv[t] = __builtin_amdgcn_mfma_f32_16x16x32_bf16(a1, *(const bf16x8*)(wd + 32 + q * 8), accv[t], 0, 0, 0);
        accv[t] = __builtin_amdgcn_mfma_f32_16x16x32_bf16(a2, *(const bf16x8*)(wd + 64 + q * 8), accv[t], 0, 0, 0);
        accv[t] = __builtin_amdgcn_mfma_f32_16x16x32_bf16(a3, *(const bf16x8*)(wd + 96 + q * 8), accv[t], 0, 0, 0);
    }
    int urow = ubase + q * 4;
#pragma unroll
    for (int t = 0; t < 4; ++t) {
        float bv = bias[t * 16 + m];
#pragma unroll
        for (int r = 0; r < 4; ++r) {
            int uu = urow + r;
            if (uu < nu) {
                u16 h = f2bf(accv[t][r] + bv);
                sbuf[(size_t)uu * 64 + t * 16 + m] = h;
                tbuf[(size_t)uu * 64 + t * 16 + m] = h;
            }
        }
    }
}

// ---- standalone final predictor ----
__global__ __launch_bounds__(256) void predl_kernel(const u16* __restrict__ xb,
        const int* __restrict__ l0, const int* __restrict__ l1,
        const float* __restrict__ pw, int ofA, int ofB,
        float* __restrict__ acc, int nl,
        const float* __restrict__ pb, float* __restrict__ out) {
    int li = blockIdx.x * 4 + (threadIdx.x >> 6);
    if (li >= nl) return;
    li = __builtin_amdgcn_readfirstlane(li);
    int lane = threadIdx.x & 63;
    int u = l0[li], v = l1[li];
    float s = pw[ofA + lane] * bf2f(xb[(size_t)u * 64 + lane])
            + pw[ofB + lane] * bf2f(xb[(size_t)v * 64 + lane]);
#pragma unroll
    for (int off = 32; off > 0; off >>= 1) s += __shfl_xor(s, off, 64);
    if (lane == 0) {
        float t = acc[li] + s + pb[0];
        t = t > 0.f ? t : 0.01f * t;
        out[li] = 1.f / (1.f + expf(-t));
    }
}

extern "C" void kernel_launch(void* const* d_in, const int* in_sizes, int n_in,
                              void* d_out, int out_size, void* d_ws, size_t ws_size,
                              hipStream_t stream) {
    const int*   se  = (const int*)d_in[0];   // [2,E] src then dst
    const int*   te  = (const int*)d_in[1];
    const int*   lk  = (const int*)d_in[2];   // [2,NLINK]
    const float* emb = (const float*)d_in[3]; // [N,64]
    const float* mw  = (const float*)d_in[4]; // [3,64,128]
    const float* mb  = (const float*)d_in[5]; // [3,64]
    const float* pw  = (const float*)d_in[6]; // [1,512]
    const float* pb  = (const float*)d_in[7]; // [1]
    float* out = (float*)d_out;

    const int E  = in_sizes[0] / 2;
    const int NL = in_sizes[2] / 2;
    const int N  = in_sizes[3] / 64;
    const int U  = 100000;
    const int NB = (N + NODESB - 1) >> BSHIFT;   // 782 coarse buckets

    char* p = (char*)d_ws;
    auto alloc = [&](size_t bytes) -> char* {
        char* r = p;
        p += (bytes + 255) & ~(size_t)255;
        return r;
    };
    u32* A     = (u32*)alloc((size_t)N * 32 * 4);   // bf16 node buf (25.6MB)
    u32* B     = (u32*)alloc((size_t)N * 32 * 4);
    u32* C     = (u32*)alloc((size_t)N * 32 * 4);   // D1: bf16(emb); later t-chain/s-chain
    u32* col_s = (u32*)alloc((size_t)E * 4);        // bin -> in-place sorted col
    u32* col_t = (u32*)alloc((size_t)E * 4);
    int* rs_s  = (int*)alloc((size_t)(N + 1) * 4);
    int* rs_t  = (int*)alloc((size_t)(N + 1) * 4);
    float* acc = (float*)alloc((size_t)NL * 4);
    int* gcnt2 = (int*)alloc(2 * NBPAD * 4);
    int* bbase_s = (int*)alloc((NBPAD + 1) * 4);
    int* bbase_t = (int*)alloc((NBPAD + 1) * 4);
    int* cur2  = (int*)alloc(2 * NBPAD * 4);
    u16* mwb   = (u16*)alloc(3 * 64 * 128 * 2);

    hipMemsetAsync(gcnt2, 0, 2 * NBPAD * 4, stream);

    const int NHIST = (E + HCHUNK - 1) / HCHUNK;     // 367
    const int NBIN  = (E + BCHUNK - 1) / BCHUNK;     // 733
    const int NWPREP = 96;
    const int NCONV = (N * 64 + 1023) / 1024;        // 12500
    const int GA    = (N + 7) / 8;                   // 25000 agg blocks (8 nodes/block)
    const int GAU   = (U + 7) / 8;                   // 12500 (layer-3 t-agg: users only)
    const int GP    = (NL + 3) / 4;                  // 25000
    const int GM    = (U + 63) / 64;                 // 1563

    // D1: hist both + W prep + emb->bf16 into C
    prep_hist<<<2 * NHIST + NWPREP + NCONV, 256, 0, stream>>>(
        se + E, te + E, E, gcnt2, mw, mwb, emb, C, N * 64, NHIST, NWPREP);
    // D2: parallel bucket scans + pred0
    scan_pred0<<<2 + GP, 256, 0, stream>>>(gcnt2, NB, bbase_s, bbase_t, cur2, rs_s, rs_t,
                                           N, emb, lk, lk + NL, pw, acc, NL);
    // D3: bin both
    bin2_kernel<<<2 * NBIN, 256, 0, stream>>>(se, se + E, te, te + E, E, cur2, col_s, col_t, NBIN);
    // D4: sort both
    sort2_kernel<<<2 * NB, 256, 0, stream>>>(col_s, col_t, bbase_s, bbase_t, rs_s, rs_t, N, NB);

    // D5: layer-1 agg, both lists from bf16(emb)=C -> A (s), B (t)
    aggp_kernel<<<2 * GA, 256, 0, stream>>>(
        C, rs_s, col_s, A, GA, C, rs_t, col_t, B, GA, N,
        (const u16*)nullptr, nullptr, nullptr, nullptr, 0, 0, nullptr, 0, 0);
    // D6: mix1 (A,B user rows)
    mix_mfma<<<GM, 256, 0, stream>>>((u16*)A, (u16*)B, mwb + 0 * 8192, mb + 0 * 64, U);
    // D7: predl1(A) + agg_s L2: A -> C
    aggp_kernel<<<GP + GA, 256, 0, stream>>>(
        A, rs_s, col_s, C, GA, nullptr, nullptr, nullptr, nullptr, 0, N,
        (const u16*)A, lk, lk + NL, pw, 64, 320, acc, NL, GP);
    // D8: agg_t L2: B -> A
    aggp_kernel<<<GA, 256, 0, stream>>>(
        B, rs_t, col_t, A, GA, nullptr, nullptr, nullptr, nullptr, 0, N,
        (const u16*)nullptr, nullptr, nullptr, nullptr, 0, 0, nullptr, 0, 0);
    // D9: mix2 (C = s-chain, A = t-chain)
    mix_mfma<<<GM, 256, 0, stream>>>((u16*)C, (u16*)A, mwb + 1 * 8192, mb + 1 * 64, U);
    // D10: predl2(C) + agg_s L3: C -> B
    aggp_kernel<<<GP + GA, 256, 0, stream>>>(
        C, rs_s, col_s, B, GA, nullptr, nullptr, nullptr, nullptr, 0, N,
        (const u16*)C, lk, lk + NL, pw, 128, 384, acc, NL, GP);
    // D11: agg_t L3 (USER dst rows only): A -> C
    aggp_kernel<<<GAU, 256, 0, stream>>>(
        A, rs_t, col_t, C, GAU, nullptr, nullptr, nullptr, nullptr, 0, U,
        (const u16*)nullptr, nullptr, nullptr, nullptr, 0, 0, nullptr, 0, 0);
    // D12: mix3 (B = s-chain, C = t-chain users)
    mix_mfma<<<GM, 256, 0, stream>>>((u16*)B, (u16*)C, mwb + 2 * 8192, mb + 2 * 64, U);
    // D13: final predictor on B (s-chain L3)
    predl_kernel<<<GP, 256, 0, stream>>>((const u16*)B, lk, lk + NL, pw, 192, 448, acc, NL, pb, out);
}

// Round 9
// 702.820 us; speedup vs baseline: 1.2723x; 1.0906x over previous
//
#include <hip/hip_runtime.h>
#include <hip/hip_bf16.h>
#include <math.h>

// N=200000 nodes, U=100000 users, D=64, L=3, E=3,000,000 per edge list, NLINK=100000.
// ws: 3 bf16 node bufs (76.8MB) + 2 bin/col (24MB, sorted in place) + aux ~= 104MB.

typedef unsigned short u16;
typedef unsigned int   u32;
typedef __attribute__((ext_vector_type(8))) short bf16x8;
typedef __attribute__((ext_vector_type(4))) float f32x4;

#define BSHIFT 8                 // 256 nodes per coarse bucket
#define NODESB 256               // nodes per bucket
#define NBPAD  1024              // padded bucket-count array (782 used)
#define BCAP   4096              // LDS staging per sort bucket (mean ~3840)
#define OVF    8                 // +2048 entries of per-thread register headroom
#define HCHUNK 8192              // edges per hist block
#define BCHUNK 8192              // edges per bin block (LDS presort)

__device__ __forceinline__ float bf2f(u16 v) {
    u32 x = ((u32)v) << 16;
    return __builtin_bit_cast(float, x);
}
__device__ __forceinline__ u16 f2bf(float f) {
    u32 x = __builtin_bit_cast(u32, f);
    u32 r = x + 0x7fffu + ((x >> 16) & 1u);   // round-to-nearest-even
    return (u16)(r >> 16);
}
__device__ __forceinline__ u32 pack2(float a, float b) {
    return (u32)f2bf(a) | ((u32)f2bf(b) << 16);
}
__device__ __forceinline__ float flo(u32 p) { return __builtin_bit_cast(float, p << 16); }
__device__ __forceinline__ float fhi(u32 p) { return __builtin_bit_cast(float, p & 0xffff0000u); }
__device__ __forceinline__ int imin(int a, int b) { return a < b ? a : b; }

// ---- D1: fused hist(s) + hist(t) + W->bf16 prep + emb->bf16 staging ----
__global__ __launch_bounds__(256) void prep_hist(const int* __restrict__ sdst,
        const int* __restrict__ tdst, int e, int* __restrict__ gcnt2,
        const float* __restrict__ mw, u16* __restrict__ mwb,
        const float* __restrict__ emb, u32* __restrict__ embb, int nelem,
        int nhist, int nwprep) {
    __shared__ int lcnt[NBPAD];
    int bid = blockIdx.x, tid = threadIdx.x;
    if (bid < 2 * nhist) {
        const int* dst = (bid < nhist) ? sdst : tdst;
        int* gcnt = gcnt2 + ((bid < nhist) ? 0 : NBPAD);
        int cb = (bid < nhist) ? bid : bid - nhist;
        for (int i = tid; i < NBPAD; i += 256) lcnt[i] = 0;
        __syncthreads();
        int base = cb * HCHUNK, end = imin(base + HCHUNK, e);
        for (int i = base + tid; i < end; i += 256)
            atomicAdd(&lcnt[(u32)dst[i] >> BSHIFT], 1);
        __syncthreads();
        for (int i = tid; i < NBPAD; i += 256)
            if (lcnt[i]) atomicAdd(&gcnt[i], lcnt[i]);
    } else if (bid < 2 * nhist + nwprep) {
        int idx = (bid - 2 * nhist) * 256 + tid;
        if (idx < 3 * 64 * 128) mwb[idx] = f2bf(mw[idx]);
    } else {
        int idx = (bid - 2 * nhist - nwprep) * 1024 + tid * 4;   // 4 floats / thread
        if (idx < nelem) {
            float4 v = *(const float4*)(emb + idx);
            uint2 r;
            r.x = pack2(v.x, v.y);
            r.y = pack2(v.z, v.w);
            *(uint2*)(embb + (idx >> 1)) = r;
        }
    }
}

// ---- D2: parallel bucket scans (2 blocks, 1024 counts @ 4/thread) + pred0 ----
__global__ __launch_bounds__(256) void scan_pred0(const int* __restrict__ gcnt2, int nb,
        int* __restrict__ bbase_s, int* __restrict__ bbase_t, int* __restrict__ cur2,
        int* __restrict__ rs_s, int* __restrict__ rs_t, int n,
        const float* __restrict__ emb, const int* __restrict__ l0, const int* __restrict__ l1,
        const float* __restrict__ pw, float* __restrict__ acc, int nl) {
    int bid = blockIdx.x;
    int tid = threadIdx.x;
    if (bid < 2) {
        __shared__ int part[256];
        const int* g = gcnt2 + bid * NBPAD;
        int* bb = bid ? bbase_t : bbase_s;
        int* cu = cur2 + bid * NBPAD;
        int* rs = bid ? rs_t : rs_s;
        int i0 = tid * 4;
        int c[4]; int s = 0;
#pragma unroll
        for (int j = 0; j < 4; ++j) { c[j] = g[i0 + j]; s += c[j]; }  // zero beyond nb
        part[tid] = s;
        __syncthreads();
        for (int off = 1; off < 256; off <<= 1) {
            int t = (tid >= off) ? part[tid - off] : 0;
            __syncthreads();
            part[tid] += t;
            __syncthreads();
        }
        int excl = part[tid] - s;
#pragma unroll
        for (int j = 0; j < 4; ++j) {
            int idx = i0 + j;
            if (idx <= nb) bb[idx] = excl;
            if (idx < nb)  cu[idx] = excl;
            excl += c[j];
        }
        if (tid == 255) rs[n] = part[255];
        return;
    }
    int li = (bid - 2) * 4 + (tid >> 6);
    if (li >= nl) return;
    li = __builtin_amdgcn_readfirstlane(li);
    int lane = tid & 63;
    int u = l0[li], v = l1[li];
    float s = pw[lane] * emb[(size_t)u * 64 + lane] + pw[256 + lane] * emb[(size_t)v * 64 + lane];
#pragma unroll
    for (int off = 32; off > 0; off >>= 1) s += __shfl_xor(s, off, 64);
    if (lane == 0) acc[li] = s;
}

// ---- D3: binning via block-local LDS presort + coalesced segment flush ----
__global__ __launch_bounds__(256) void bin3_kernel(const int* __restrict__ ssrc,
        const int* __restrict__ sdst, const int* __restrict__ tsrc, const int* __restrict__ tdst,
        int e, int* __restrict__ cur2, u32* __restrict__ bin_s, u32* __restrict__ bin_t,
        int nbin) {
    __shared__ u32 stage[BCHUNK];       // 32KB bucket-sorted staging
    __shared__ int lcnt[NBPAD];         // hist -> scatter cursor
    __shared__ int lofs[NBPAD];         // bucket start within stage
    __shared__ int lbase[NBPAD];        // reserved global base
    __shared__ int part[256];
    int bid = blockIdx.x, tid = threadIdx.x;
    const int* src; const int* dst; int* cursor; u32* bin; int cb;
    if (bid < nbin) { src = ssrc; dst = sdst; cursor = cur2; bin = bin_s; cb = bid; }
    else { src = tsrc; dst = tdst; cursor = cur2 + NBPAD; bin = bin_t; cb = bid - nbin; }
    for (int i = tid; i < NBPAD; i += 256) lcnt[i] = 0;
    __syncthreads();
    int base = cb * BCHUNK, end = imin(base + BCHUNK, e);
    // A: histogram chunk by bucket
    for (int i = base + tid; i < end; i += 256)
        atomicAdd(&lcnt[(u32)dst[i] >> BSHIFT], 1);
    __syncthreads();
    // B: block scan -> lofs; bulk global reservation -> lbase; cursor := lofs
    {
        int i0 = tid * 4;
        int c[4]; int s = 0;
#pragma unroll
        for (int j = 0; j < 4; ++j) { c[j] = lcnt[i0 + j]; s += c[j]; }
        part[tid] = s;
        __syncthreads();
        for (int off = 1; off < 256; off <<= 1) {
            int t = (tid >= off) ? part[tid - off] : 0;
            __syncthreads();
            part[tid] += t;
            __syncthreads();
        }
        int excl = part[tid] - s;
#pragma unroll
        for (int j = 0; j < 4; ++j) {
            int idx = i0 + j;
            lofs[idx]  = excl;
            lbase[idx] = c[j] ? atomicAdd(&cursor[idx], c[j]) : 0;
            lcnt[idx]  = excl;          // scatter cursor starts at bucket start
            excl += c[j];
        }
    }
    __syncthreads();
    // C: scatter entries into LDS staging, bucket-sorted
    for (int i = base + tid; i < end; i += 256) {
        int d = dst[i];
        int b = (u32)d >> BSHIFT;
        int p = atomicAdd(&lcnt[b], 1);
        stage[p] = (u32)src[i] | ((u32)(d & (NODESB - 1)) << 18);   // src < 2^18
    }
    __syncthreads();
    // D: flush segments, 4 lanes per bucket -> contiguous burst writes
    for (int bb = tid >> 2; bb < NBPAD; bb += 64) {
        int lo = lofs[bb];
        int cnt = lcnt[bb] - lo;
        int gb = lbase[bb];
        for (int j = tid & 3; j < cnt; j += 4)
            bin[gb + j] = stage[lo + j];
    }
}

// ---- D4: fused per-bucket counting sort (both lists), in place ----
__global__ __launch_bounds__(256) void sort2_kernel(u32* __restrict__ bin_s, u32* __restrict__ bin_t,
        const int* __restrict__ bbase_s, const int* __restrict__ bbase_t,
        int* __restrict__ rs_s, int* __restrict__ rs_t, int n, int nb) {
    __shared__ u32 ent[BCAP];
    __shared__ int cnt[NODESB];
    __shared__ int part[256];
    int bid = blockIdx.x, tid = threadIdx.x;
    u32* bin; const int* bbase; int* rowstart; int b;
    if (bid < nb) { bin = bin_s; bbase = bbase_s; rowstart = rs_s; b = bid; }
    else { bin = bin_t; bbase = bbase_t; rowstart = rs_t; b = bid - nb; }
    int beg = bbase[b], end = bbase[b + 1];
    int sz = end - beg;
    cnt[tid] = 0;
    __syncthreads();
    u32 ovf[OVF];
    for (int i = tid; i < sz; i += 256) {
        u32 v = bin[beg + i];
        if (i < BCAP) ent[i] = v;
        else { int k = (i - BCAP) >> 8; if (k < OVF) ovf[k] = v; }
        atomicAdd(&cnt[v >> 18], 1);
    }
    __syncthreads();
    int c = cnt[tid];
    part[tid] = c;
    __syncthreads();
    for (int off = 1; off < 256; off <<= 1) {
        int t = (tid >= off) ? part[tid - off] : 0;
        __syncthreads();
        part[tid] += t;
        __syncthreads();
    }
    int excl = part[tid] - c;
    int node = (b << BSHIFT) + tid;
    if (node < n) rowstart[node] = beg + excl;
    cnt[tid] = excl;             // running cursor for scatter phase
    __syncthreads();
    for (int i = tid; i < sz; i += 256) {
        u32 v;
        if (i < BCAP) v = ent[i];
        else { int k = (i - BCAP) >> 8; v = (k < OVF) ? ovf[k] : bin[beg + i]; }
        int pos = atomicAdd(&cnt[v >> 18], 1);
        bin[beg + pos] = v & 0x3FFFFu;
    }
}

// ---- mean aggregation (bf16 in/out) + optional fused predictor blocks ----
// TWO nodes per wave (32 lanes each); 8 lanes/edge (uint4 = 16B), 4 edge groups,
// 16-slot blocks with FOUR row loads in flight per node -> 8 gathers/wave.
// Clamped slots overcount row[col[dgm1]] (only possible in the last block),
// removed by conditional subtracts after the loop.
__global__ __launch_bounds__(256) void aggp_kernel(
        const u32* __restrict__ x0, const int* __restrict__ rsA, const u32* __restrict__ colA,
        u32* __restrict__ outA, int nblkA,
        const u32* __restrict__ x1, const int* __restrict__ rsB, const u32* __restrict__ colB,
        u32* __restrict__ outB, int nblkB, int n,
        const u16* __restrict__ px, const int* __restrict__ l0, const int* __restrict__ l1,
        const float* __restrict__ pw, int ofA, int ofB, float* __restrict__ acc, int nl,
        int npred) {
    int bid = blockIdx.x;
    int lane = threadIdx.x & 63;
    if (bid < npred) {
        int li = bid * 4 + (threadIdx.x >> 6);
        if (li >= nl) return;
        li = __builtin_amdgcn_readfirstlane(li);
        int u = l0[li], v = l1[li];
        float s = pw[ofA + lane] * bf2f(px[(size_t)u * 64 + lane])
                + pw[ofB + lane] * bf2f(px[(size_t)v * 64 + lane]);
#pragma unroll
        for (int off = 32; off > 0; off >>= 1) s += __shfl_xor(s, off, 64);
        if (lane == 0) acc[li] += s;
        return;
    }
    bid -= npred;
    const u32* xin; const int* rs; const u32* col; u32* out;
    if (bid < nblkA) { xin = x0; rs = rsA; col = colA; out = outA; }
    else { bid -= nblkA; xin = x1; rs = rsB; col = colB; out = outB; }
    int node = bid * 8 + (threadIdx.x >> 5);   // one node per 32-lane half-wave
    if (node >= n) return;
    int fl = lane & 7;           // feature octet: features 8fl .. 8fl+7
    int g  = (lane >> 3) & 3;    // edge group 0..3 within the half-wave
    int beg = rs[node];
    int dgv = rs[node + 1] - beg;
    int dgm1 = dgv - 1;
    float a0 = 0.f, a1 = 0.f, a2 = 0.f, a3 = 0.f, a4 = 0.f, a5 = 0.f, a6 = 0.f, a7 = 0.f;
    uint4 p0 = make_uint4(0, 0, 0, 0), p1 = make_uint4(0, 0, 0, 0);
    uint4 p2 = make_uint4(0, 0, 0, 0), p3 = make_uint4(0, 0, 0, 0);
    const uint4* xb = (const uint4*)xin;
    if (dgv > 0) {
        int s0 = col[beg + imin(g, dgm1)];
        int s1 = col[beg + imin(g + 4, dgm1)];
        int s2 = col[beg + imin(g + 8, dgm1)];
        int s3 = col[beg + imin(g + 12, dgm1)];
        for (int jb = 0; jb < dgv; jb += 16) {
            p0 = xb[(size_t)s0 * 8 + fl];
            p1 = xb[(size_t)s1 * 8 + fl];
            p2 = xb[(size_t)s2 * 8 + fl];
            p3 = xb[(size_t)s3 * 8 + fl];
            int nj = jb + 16 + g;
            s0 = col[beg + imin(nj, dgm1)];       // prefetch next block's cols
            s1 = col[beg + imin(nj + 4, dgm1)];
            s2 = col[beg + imin(nj + 8, dgm1)];
            s3 = col[beg + imin(nj + 12, dgm1)];
            a0 += (flo(p0.x) + flo(p1.x)) + (flo(p2.x) + flo(p3.x));
            a1 += (fhi(p0.x) + fhi(p1.x)) + (fhi(p2.x) + fhi(p3.x));
            a2 += (flo(p0.y) + flo(p1.y)) + (flo(p2.y) + flo(p3.y));
            a3 += (fhi(p0.y) + fhi(p1.y)) + (fhi(p2.y) + fhi(p3.y));
            a4 += (flo(p0.z) + flo(p1.z)) + (flo(p2.z) + flo(p3.z));
            a5 += (fhi(p0.z) + fhi(p1.z)) + (fhi(p2.z) + fhi(p3.z));
            a6 += (flo(p0.w) + flo(p1.w)) + (flo(p2.w) + flo(p3.w));
            a7 += (fhi(p0.w) + fhi(p1.w)) + (fhi(p2.w) + fhi(p3.w));
        }
        int jbl = (dgm1 >> 4) << 4;               // last iteration's block base
        if (jbl + g > dgm1) {
            a0 -= flo(p0.x); a1 -= fhi(p0.x); a2 -= flo(p0.y); a3 -= fhi(p0.y);
            a4 -= flo(p0.z); a5 -= fhi(p0.z); a6 -= flo(p0.w); a7 -= fhi(p0.w);
        }
        if (jbl + 4 + g > dgm1) {
            a0 -= flo(p1.x); a1 -= fhi(p1.x); a2 -= flo(p1.y); a3 -= fhi(p1.y);
            a4 -= flo(p1.z); a5 -= fhi(p1.z); a6 -= flo(p1.w); a7 -= fhi(p1.w);
        }
        if (jbl + 8 + g > dgm1) {
            a0 -= flo(p2.x); a1 -= fhi(p2.x); a2 -= flo(p2.y); a3 -= fhi(p2.y);
            a4 -= flo(p2.z); a5 -= fhi(p2.z); a6 -= flo(p2.w); a7 -= fhi(p2.w);
        }
        if (jbl + 12 + g > dgm1) {
            a0 -= flo(p3.x); a1 -= fhi(p3.x); a2 -= flo(p3.y); a3 -= fhi(p3.y);
            a4 -= flo(p3.z); a5 -= fhi(p3.z); a6 -= flo(p3.w); a7 -= fhi(p3.w);
        }
    }
#pragma unroll
    for (int off = 8; off <= 16; off <<= 1) {     // reduce over 4 edge groups
        a0 += __shfl_xor(a0, off, 64); a1 += __shfl_xor(a1, off, 64);
        a2 += __shfl_xor(a2, off, 64); a3 += __shfl_xor(a3, off, 64);
        a4 += __shfl_xor(a4, off, 64); a5 += __shfl_xor(a5, off, 64);
        a6 += __shfl_xor(a6, off, 64); a7 += __shfl_xor(a7, off, 64);
    }
    if (g == 0) {
        float inv = __builtin_amdgcn_rcpf((float)(dgv > 1 ? dgv : 1));
        uint4 r;
        r.x = pack2(a0 * inv, a1 * inv);
        r.y = pack2(a2 * inv, a3 * inv);
        r.z = pack2(a4 * inv, a5 * inv);
        r.w = pack2(a6 * inv, a7 * inv);
        ((uint4*)out)[(size_t)node * 8 + fl] = r;
    }
}

// ---- user mix via MFMA: one wave = 16 users, K=128 (sbuf||tbuf), 64 outputs ----
__global__ __launch_bounds__(256) void mix_mfma(u16* __restrict__ sbuf, u16* __restrict__ tbuf,
        const u16* __restrict__ wb /*[64][128] bf16*/, const float* __restrict__ bias, int nu) {
    int lane = threadIdx.x & 63;
    int wv = threadIdx.x >> 6;
    int m = lane & 15, q = lane >> 4;
    int ubase = blockIdx.x * 64 + wv * 16;
    int ul = ubase + m;
    int usafe = ul < nu ? ul : nu - 1;
    const bf16x8* srow = (const bf16x8*)(sbuf + (size_t)usafe * 64);
    const bf16x8* trow = (const bf16x8*)(tbuf + (size_t)usafe * 64);
    bf16x8 a0 = srow[q];
    bf16x8 a1 = srow[4 + q];
    bf16x8 a2 = trow[q];
    bf16x8 a3 = trow[4 + q];
    f32x4 accv[4];
#pragma unroll
    for (int t = 0; t < 4; ++t) { accv[t].x = accv[t].y = accv[t].z = accv[t].w = 0.f; }
#pragma unroll
    for (int t = 0; t < 4; ++t) {
        const u16* wd = wb + (size_t)(t * 16 + m) * 128;
        accv[t] = __builtin_amdgcn_mfma_f32_16x16x32_bf16(a0, *(const bf16x8*)(wd + q * 8), accv[t], 0, 0, 0);
        accv[t] = __builtin_amdgcn_mfma_f32_16x16x32_bf16(a1, *(const bf16x8*)(wd + 32 + q * 8), accv[t], 0, 0, 0);
        accv[t] = __builtin_amdgcn_mfma_f32_16x16x32_bf16(a2, *(const bf16x8*)(wd + 64 + q * 8), accv[t], 0, 0, 0);
        accv[t] = __builtin_amdgcn_mfma_f32_16x16x32_bf16(a3, *(const bf16x8*)(wd + 96 + q * 8), accv[t], 0, 0, 0);
    }
    int urow = ubase + q * 4;
#pragma unroll
    for (int t = 0; t < 4; ++t) {
        float bv = bias[t * 16 + m];
#pragma unroll
        for (int r = 0; r < 4; ++r) {
            int uu = urow + r;
            if (uu < nu) {
                u16 h = f2bf(accv[t][r] + bv);
                sbuf[(size_t)uu * 64 + t * 16 + m] = h;
                tbuf[(size_t)uu * 64 + t * 16 + m] = h;
            }
        }
    }
}

// ---- standalone final predictor ----
__global__ __launch_bounds__(256) void predl_kernel(const u16* __restrict__ xb,
        const int* __restrict__ l0, const int* __restrict__ l1,
        const float* __restrict__ pw, int ofA, int ofB,
        float* __restrict__ acc, int nl,
        const float* __restrict__ pb, float* __restrict__ out) {
    int li = blockIdx.x * 4 + (threadIdx.x >> 6);
    if (li >= nl) return;
    li = __builtin_amdgcn_readfirstlane(li);
    int lane = threadIdx.x & 63;
    int u = l0[li], v = l1[li];
    float s = pw[ofA + lane] * bf2f(xb[(size_t)u * 64 + lane])
            + pw[ofB + lane] * bf2f(xb[(size_t)v * 64 + lane]);
#pragma unroll
    for (int off = 32; off > 0; off >>= 1) s += __shfl_xor(s, off, 64);
    if (lane == 0) {
        float t = acc[li] + s + pb[0];
        t = t > 0.f ? t : 0.01f * t;
        out[li] = 1.f / (1.f + expf(-t));
    }
}

extern "C" void kernel_launch(void* const* d_in, const int* in_sizes, int n_in,
                              void* d_out, int out_size, void* d_ws, size_t ws_size,
                              hipStream_t stream) {
    const int*   se  = (const int*)d_in[0];   // [2,E] src then dst
    const int*   te  = (const int*)d_in[1];
    const int*   lk  = (const int*)d_in[2];   // [2,NLINK]
    const float* emb = (const float*)d_in[3]; // [N,64]
    const float* mw  = (const float*)d_in[4]; // [3,64,128]
    const float* mb  = (const float*)d_in[5]; // [3,64]
    const float* pw  = (const float*)d_in[6]; // [1,512]
    const float* pb  = (const float*)d_in[7]; // [1]
    float* out = (float*)d_out;

    const int E  = in_sizes[0] / 2;
    const int NL = in_sizes[2] / 2;
    const int N  = in_sizes[3] / 64;
    const int U  = 100000;
    const int NB = (N + NODESB - 1) >> BSHIFT;   // 782 coarse buckets

    char* p = (char*)d_ws;
    auto alloc = [&](size_t bytes) -> char* {
        char* r = p;
        p += (bytes + 255) & ~(size_t)255;
        return r;
    };
    u32* A     = (u32*)alloc((size_t)N * 32 * 4);   // bf16 node buf (25.6MB)
    u32* B     = (u32*)alloc((size_t)N * 32 * 4);
    u32* C     = (u32*)alloc((size_t)N * 32 * 4);   // D1: bf16(emb); later t-chain/s-chain
    u32* col_s = (u32*)alloc((size_t)E * 4);        // bin -> in-place sorted col
    u32* col_t = (u32*)alloc((size_t)E * 4);
    int* rs_s  = (int*)alloc((size_t)(N + 1) * 4);
    int* rs_t  = (int*)alloc((size_t)(N + 1) * 4);
    float* acc = (float*)alloc((size_t)NL * 4);
    int* gcnt2 = (int*)alloc(2 * NBPAD * 4);
    int* bbase_s = (int*)alloc((NBPAD + 1) * 4);
    int* bbase_t = (int*)alloc((NBPAD + 1) * 4);
    int* cur2  = (int*)alloc(2 * NBPAD * 4);
    u16* mwb   = (u16*)alloc(3 * 64 * 128 * 2);

    hipMemsetAsync(gcnt2, 0, 2 * NBPAD * 4, stream);

    const int NHIST = (E + HCHUNK - 1) / HCHUNK;     // 367
    const int NBIN  = (E + BCHUNK - 1) / BCHUNK;     // 367
    const int NWPREP = 96;
    const int NCONV = (N * 64 + 1023) / 1024;        // 12500
    const int GA    = (N + 7) / 8;                   // 25000 agg blocks (8 nodes/block)
    const int GAU   = (U + 7) / 8;                   // 12500 (layer-3 t-agg: users only)
    const int GP    = (NL + 3) / 4;                  // 25000
    const int GM    = (U + 63) / 64;                 // 1563

    // D1: hist both + W prep + emb->bf16 into C
    prep_hist<<<2 * NHIST + NWPREP + NCONV, 256, 0, stream>>>(
        se + E, te + E, E, gcnt2, mw, mwb, emb, C, N * 64, NHIST, NWPREP);
    // D2: parallel bucket scans + pred0
    scan_pred0<<<2 + GP, 256, 0, stream>>>(gcnt2, NB, bbase_s, bbase_t, cur2, rs_s, rs_t,
                                           N, emb, lk, lk + NL, pw, acc, NL);
    // D3: bin both (LDS presort)
    bin3_kernel<<<2 * NBIN, 256, 0, stream>>>(se, se + E, te, te + E, E, cur2, col_s, col_t, NBIN);
    // D4: sort both
    sort2_kernel<<<2 * NB, 256, 0, stream>>>(col_s, col_t, bbase_s, bbase_t, rs_s, rs_t, N, NB);

    // D5: layer-1 agg, both lists from bf16(emb)=C -> A (s), B (t)
    aggp_kernel<<<2 * GA, 256, 0, stream>>>(
        C, rs_s, col_s, A, GA, C, rs_t, col_t, B, GA, N,
        (const u16*)nullptr, nullptr, nullptr, nullptr, 0, 0, nullptr, 0, 0);
    // D6: mix1 (A,B user rows)
    mix_mfma<<<GM, 256, 0, stream>>>((u16*)A, (u16*)B, mwb + 0 * 8192, mb + 0 * 64, U);
    // D7: predl1(A) + agg_s L2: A -> C
    aggp_kernel<<<GP + GA, 256, 0, stream>>>(
        A, rs_s, col_s, C, GA, nullptr, nullptr, nullptr, nullptr, 0, N,
        (const u16*)A, lk, lk + NL, pw, 64, 320, acc, NL, GP);
    // D8: agg_t L2: B -> A
    aggp_kernel<<<GA, 256, 0, stream>>>(
        B, rs_t, col_t, A, GA, nullptr, nullptr, nullptr, nullptr, 0, N,
        (const u16*)nullptr, nullptr, nullptr, nullptr, 0, 0, nullptr, 0, 0);
    // D9: mix2 (C = s-chain, A = t-chain)
    mix_mfma<<<GM, 256, 0, stream>>>((u16*)C, (u16*)A, mwb + 1 * 8192, mb + 1 * 64, U);
    // D10: predl2(C) + agg_s L3: C -> B
    aggp_kernel<<<GP + GA, 256, 0, stream>>>(
        C, rs_s, col_s, B, GA, nullptr, nullptr, nullptr, nullptr, 0, N,
        (const u16*)C, lk, lk + NL, pw, 128, 384, acc, NL, GP);
    // D11: agg_t L3 (USER dst rows only): A -> C
    aggp_kernel<<<GAU, 256, 0, stream>>>(
        A, rs_t, col_t, C, GAU, nullptr, nullptr, nullptr, nullptr, 0, U,
        (const u16*)nullptr, nullptr, nullptr, nullptr, 0, 0, nullptr, 0, 0);
    // D12: mix3 (B = s-chain, C = t-chain users)
    mix_mfma<<<GM, 256, 0, stream>>>((u16*)B, (u16*)C, mwb + 2 * 8192, mb + 2 * 64, U);
    // D13: final predictor on B (s-chain L3)
    predl_kernel<<<GP, 256, 0, stream>>>((const u16*)B, lk, lk + NL, pw, 192, 448, acc, NL, pb, out);
}